// Round 1
// baseline (2709.631 us; speedup 1.0000x reference)
//
#include <hip/hip_runtime.h>
#include <cstdint>
#include <cstddef>

// ---------------- types ----------------
typedef __bf16 bf16_t;
typedef bf16_t bf16x8 __attribute__((ext_vector_type(8)));
typedef float  f32x4  __attribute__((ext_vector_type(4)));

#define GAS __attribute__((address_space(1)))
#define LAS __attribute__((address_space(3)))

__device__ __forceinline__ void g2l16(const void* g, void* l) {
  // async global->LDS, 16B per lane; LDS dest is wave-uniform base + lane*16
  __builtin_amdgcn_global_load_lds((const GAS unsigned int*)g,
                                   (LAS unsigned int*)l, 16, 0, 0);
}

// Problem constants
#define HW_  65536      // 256*256
#define NPIX 4096       // 64*64 patch grid
#define KC   2432       // 3*800 + 32 pad (hi/lo split concat K)
#define NP   896        // 784 padded to 7*128
#define LDA_Q 2432
#define LDC_S 4096

// ---------------- 1x1 convs: b1=gw*s+gb, b2=tw*g+tb, b3=pw*g+pb ----------------
__global__ __launch_bounds__(256) void conv1x1_3(
    const float* __restrict__ bo, const float* __restrict__ dg,
    const float* __restrict__ gw, const float* __restrict__ gb,
    const float* __restrict__ tw, const float* __restrict__ tb,
    const float* __restrict__ pw, const float* __restrict__ pb,
    float* __restrict__ b1, float* __restrict__ b2, float* __restrict__ b3)
{
  __shared__ float w1[1024], w2[1024], w3[1024], bia[48];
  int tid = threadIdx.x;
  for (int i = tid; i < 1024; i += 256) { w1[i] = gw[i]; w2[i] = tw[i]; w3[i] = pw[i]; }
  if (tid < 16) { bia[tid] = gb[tid]; bia[16 + tid] = tb[tid]; bia[32 + tid] = pb[tid]; }
  __syncthreads();
  int hw = blockIdx.x * 256 + tid;
  float a1[16], a2[16], a3[16];
#pragma unroll
  for (int o = 0; o < 16; ++o) { a1[o] = bia[o]; a2[o] = bia[16 + o]; a3[o] = bia[32 + o]; }
  for (int c = 0; c < 64; ++c) {
    float vs = bo[(size_t)c * HW_ + hw];
    float vg = dg[(size_t)c * HW_ + hw];
#pragma unroll
    for (int o = 0; o < 16; ++o) {
      a1[o] = fmaf(w1[o * 64 + c], vs, a1[o]);
      a2[o] = fmaf(w2[o * 64 + c], vg, a2[o]);
      a3[o] = fmaf(w3[o * 64 + c], vg, a3[o]);
    }
  }
#pragma unroll
  for (int o = 0; o < 16; ++o) {
    b1[(size_t)o * HW_ + hw] = a1[o];
    b2[(size_t)o * HW_ + hw] = a2[o];
    b3[(size_t)o * HW_ + hw] = a3[o];
  }
}

// ---------------- unfold (k=7,s=4,pad 1/2) into [4096][2432] bf16 hi/lo-split ----------------
// mode 0 (q): parts [hi | hi | lo] ; mode 1 (k): parts [hi | lo | hi]
// score = sum_parts q'.k' = qhi*khi + qhi*klo + qlo*khi  (~fp32 accurate)
__global__ __launch_bounds__(256) void unfold_qk(const float* __restrict__ src,
                                                 bf16_t* __restrict__ dst, int mode)
{
  int kk = blockIdx.x * 256 + threadIdx.x;   // [0,1024) use [0,832)
  int i  = blockIdx.y;                        // patch index (oy*64+ox)
  if (kk >= 832) return;
  size_t rowoff = (size_t)i * KC;
  if (kk >= 800) { dst[rowoff + 1600 + kk] = (bf16_t)0.f; return; }  // [2400,2432) zeros
  float val = 0.f;
  if (kk < 784) {
    int c = kk / 49; int r = kk - c * 49; int ki = r / 7; int kj = r - ki * 7;
    int oy = i >> 6, ox = i & 63;
    int y = oy * 4 + ki - 1, x = ox * 4 + kj - 1;
    if ((unsigned)y < 256u && (unsigned)x < 256u) val = src[(size_t)c * HW_ + y * 256 + x];
  }
  bf16_t hi = (bf16_t)val;
  bf16_t lo = (bf16_t)(val - (float)hi);
  dst[rowoff + kk]        = hi;
  dst[rowoff + 800 + kk]  = mode ? lo : hi;
  dst[rowoff + 1600 + kk] = mode ? hi : lo;
}

// v unfold: vbuf[p][j] (NP=896 rows, 4096 cols) bf16; rows >=784 are zero
__global__ __launch_bounds__(256) void unfold_v(const float* __restrict__ src,
                                                bf16_t* __restrict__ vb)
{
  int j = blockIdx.x * 256 + threadIdx.x;
  int p = blockIdx.y;
  float val = 0.f;
  if (p < 784) {
    int c = p / 49; int r = p - c * 49; int ki = r / 7; int kj = r - ki * 7;
    int oy = j >> 6, ox = j & 63;
    int y = oy * 4 + ki - 1, x = ox * 4 + kj - 1;
    if ((unsigned)y < 256u && (unsigned)x < 256u) val = src[(size_t)c * HW_ + y * 256 + x];
  }
  vb[(size_t)p * 4096 + j] = (bf16_t)val;
}

// ---------------- GEMM: C[M][N] = alpha * A(MxK,row-major) * B(NxK,row-major)^T ----------------
// m97 structure: 128x128 tile, BK=32, 4 waves each 64x64, global_load_lds(16B) staging.
__global__ __launch_bounds__(256) void gemm_nt(
    const bf16_t* __restrict__ A, int lda,
    const bf16_t* __restrict__ B, int ldb,
    float* __restrict__ C, int ldc,
    int N, int K, float alpha)
{
  __shared__ __align__(16) bf16_t lA[128 * 32];
  __shared__ __align__(16) bf16_t lB[128 * 32];
  int nbn = N >> 7;
  int nwg = gridDim.x;
  int wg  = blockIdx.x;
  int swz = ((nwg & 7) == 0) ? ((wg & 7) * (nwg >> 3) + (wg >> 3)) : wg;  // XCD swizzle
  int bm = swz / nbn, bn = swz - bm * nbn;

  int tid  = threadIdx.x;
  int lane = tid & 63, wid = tid >> 6;
  int wm = (wid >> 1) * 64, wn = (wid & 1) * 64;
  int l16 = lane & 15, lk8 = (lane >> 4) * 8;

  // staging: slot t -> row=t>>2, k8=t&3 (linear LDS, 16B per slot)
  const bf16_t* ga0 = A + (size_t)(bm * 128 + (tid >> 2)) * lda + (tid & 3) * 8;
  const bf16_t* ga1 = ga0 + (size_t)64 * lda;
  const bf16_t* gb0 = B + (size_t)(bn * 128 + (tid >> 2)) * ldb + (tid & 3) * 8;
  const bf16_t* gb1 = gb0 + (size_t)64 * ldb;
  bf16_t* la0 = &lA[(size_t)tid * 8];
  bf16_t* la1 = &lA[(size_t)(tid + 256) * 8];
  bf16_t* lb0 = &lB[(size_t)tid * 8];
  bf16_t* lb1 = &lB[(size_t)(tid + 256) * 8];

  f32x4 acc[4][4];
#pragma unroll
  for (int i = 0; i < 4; ++i)
#pragma unroll
    for (int j = 0; j < 4; ++j) acc[i][j] = f32x4{0.f, 0.f, 0.f, 0.f};

  for (int k0 = 0; k0 < K; k0 += 32) {
    g2l16(ga0 + k0, la0);
    g2l16(ga1 + k0, la1);
    g2l16(gb0 + k0, lb0);
    g2l16(gb1 + k0, lb1);
    __syncthreads();   // drains vmcnt -> staged data visible
    bf16x8 af[4], bv[4];
#pragma unroll
    for (int f = 0; f < 4; ++f) {
      af[f] = *(const bf16x8*)&lA[(wm + f * 16 + l16) * 32 + lk8];
      bv[f] = *(const bf16x8*)&lB[(wn + f * 16 + l16) * 32 + lk8];
    }
#pragma unroll
    for (int i = 0; i < 4; ++i)
#pragma unroll
      for (int j = 0; j < 4; ++j)
        acc[i][j] = __builtin_amdgcn_mfma_f32_16x16x32_bf16(af[i], bv[j], acc[i][j], 0, 0, 0);
    __syncthreads();   // protect LDS before next stage
  }

  // C/D layout (m89-verified): col = lane&15, row = (lane>>4)*4 + reg
  int r0 = bm * 128 + wm + (lane >> 4) * 4;
  int c0 = bn * 128 + wn + l16;
#pragma unroll
  for (int i = 0; i < 4; ++i)
#pragma unroll
    for (int j = 0; j < 4; ++j) {
      float* cp = C + (size_t)(r0 + i * 16) * ldc + c0 + j * 16;
#pragma unroll
      for (int r = 0; r < 4; ++r) cp[(size_t)r * ldc] = alpha * acc[i][j][r];
    }
}

// ---------------- fused row softmax: att = softmax(score) as bf16 ----------------
__global__ __launch_bounds__(256) void softmax_rows(const float* __restrict__ S,
                                                    bf16_t* __restrict__ Att)
{
  int row = blockIdx.x;
  int tid = threadIdx.x;
  int lane = tid & 63, wid = tid >> 6;
  const float4* Sp = (const float4*)(S + (size_t)row * 4096);
  float4 vv[4];
  float m = -3.4e38f;
#pragma unroll
  for (int u = 0; u < 4; ++u) {
    vv[u] = Sp[u * 256 + tid];
    m = fmaxf(m, fmaxf(fmaxf(vv[u].x, vv[u].y), fmaxf(vv[u].z, vv[u].w)));
  }
#pragma unroll
  for (int off = 32; off; off >>= 1) m = fmaxf(m, __shfl_xor(m, off));
  __shared__ float redm[4], reds[4];
  if (lane == 0) redm[wid] = m;
  __syncthreads();
  m = fmaxf(fmaxf(redm[0], redm[1]), fmaxf(redm[2], redm[3]));
  float ssum = 0.f;
#pragma unroll
  for (int u = 0; u < 4; ++u) {
    vv[u].x = __expf(vv[u].x - m); vv[u].y = __expf(vv[u].y - m);
    vv[u].z = __expf(vv[u].z - m); vv[u].w = __expf(vv[u].w - m);
    ssum += vv[u].x + vv[u].y + vv[u].z + vv[u].w;
  }
#pragma unroll
  for (int off = 32; off; off >>= 1) ssum += __shfl_xor(ssum, off);
  if (lane == 0) reds[wid] = ssum;
  __syncthreads();
  float inv = 1.0f / (reds[0] + reds[1] + reds[2] + reds[3]);
  ushort4* Ap = (ushort4*)(Att + (size_t)row * 4096);
#pragma unroll
  for (int u = 0; u < 4; ++u) {
    union { bf16_t b[4]; ushort4 q; } pk;
    pk.b[0] = (bf16_t)(vv[u].x * inv);
    pk.b[1] = (bf16_t)(vv[u].y * inv);
    pk.b[2] = (bf16_t)(vv[u].z * inv);
    pk.b[3] = (bf16_t)(vv[u].w * inv);
    Ap[u * 256 + tid] = pk.q;
  }
}

// ---------------- fold (k=7,s=4,pad=3) + mask normalize -> zi[16][256][256] ----------------
__global__ __launch_bounds__(256) void fold_norm(const float* __restrict__ amv,
                                                 float* __restrict__ zi)
{
  int idx = blockIdx.x * 256 + threadIdx.x;   // c*65536 + h*256 + w
  int c = idx >> 16;
  int h = (idx >> 8) & 255;
  int w = idx & 255;
  int t = h + 3, u = w + 3;
  int oy0 = (t - 3) >> 2, oy1 = min(63, t >> 2);
  int ox0 = (u - 3) >> 2, ox1 = min(63, u >> 2);
  float sum = 0.f;
  for (int oy = oy0; oy <= oy1; ++oy) {
    int ki = t - oy * 4;
    for (int ox = ox0; ox <= ox1; ++ox) {
      int kj = u - ox * 4;
      sum += amv[(size_t)(oy * 64 + ox) * NP + c * 49 + ki * 7 + kj];
    }
  }
  int cnt = (oy1 - oy0 + 1) * (ox1 - ox0 + 1);
  zi[idx] = sum / (float)cnt;
}

// ---------------- final: out = bo + w_w*zi + w_b ----------------
__global__ __launch_bounds__(256) void out_conv(const float* __restrict__ zi,
                                                const float* __restrict__ bo,
                                                const float* __restrict__ ww,
                                                const float* __restrict__ wb,
                                                float* __restrict__ outb)
{
  __shared__ float wws[1024], wbs[64];
  int tid = threadIdx.x;
  for (int i = tid; i < 1024; i += 256) wws[i] = ww[i];
  if (tid < 64) wbs[tid] = wb[tid];
  __syncthreads();
  int hw = blockIdx.x * 256 + tid;
  float z[16];
#pragma unroll
  for (int c = 0; c < 16; ++c) z[c] = zi[(size_t)c * HW_ + hw];
  for (int o = 0; o < 64; ++o) {
    float a = wbs[o];
#pragma unroll
    for (int c = 0; c < 16; ++c) a = fmaf(wws[o * 16 + c], z[c], a);
    outb[(size_t)o * HW_ + hw] = bo[(size_t)o * HW_ + hw] + a;
  }
}

// ---------------- host orchestration ----------------
static inline size_t alup(size_t x) { return (x + 255) & ~(size_t)255; }

extern "C" void kernel_launch(void* const* d_in, const int* in_sizes, int n_in,
                              void* d_out, int out_size, void* d_ws, size_t ws_size,
                              hipStream_t stream) {
  const float* s   = (const float*)d_in[0];
  const float* g   = (const float*)d_in[1];
  const float* g_w = (const float*)d_in[2];
  const float* g_b = (const float*)d_in[3];
  const float* t_w = (const float*)d_in[4];
  const float* t_b = (const float*)d_in[5];
  const float* p_w = (const float*)d_in[6];
  const float* p_b = (const float*)d_in[7];
  const float* w_w = (const float*)d_in[8];
  const float* w_b = (const float*)d_in[9];
  float* out = (float*)d_out;

  uint8_t* wp = (uint8_t*)d_ws;
  float*  b1    = (float*)wp;  wp += alup((size_t)16 * HW_ * 4);
  float*  b2    = (float*)wp;  wp += alup((size_t)16 * HW_ * 4);
  float*  b3    = (float*)wp;  wp += alup((size_t)16 * HW_ * 4);
  bf16_t* qbuf  = (bf16_t*)wp; wp += alup((size_t)NPIX * KC * 2);
  bf16_t* kbuf  = (bf16_t*)wp; wp += alup((size_t)NPIX * KC * 2);
  bf16_t* vbuf  = (bf16_t*)wp; wp += alup((size_t)NP * 4096 * 2);
  float*  score = (float*)wp;  wp += alup((size_t)NPIX * NPIX * 4);
  bf16_t* att   = (bf16_t*)wp; wp += alup((size_t)NPIX * NPIX * 2);
  float*  amv   = (float*)wp;  wp += alup((size_t)NPIX * NP * 4);
  float*  zi    = (float*)wp;  wp += alup((size_t)16 * HW_ * 4);
  // total ~180 MB

  for (int b = 0; b < 8; ++b) {
    const float* bo = s + (size_t)b * 64 * HW_;
    const float* dg = g + (size_t)b * 64 * HW_;
    float* ob = out + (size_t)b * 64 * HW_;

    conv1x1_3<<<dim3(256), dim3(256), 0, stream>>>(bo, dg, g_w, g_b, t_w, t_b, p_w, p_b,
                                                   b1, b2, b3);
    unfold_qk<<<dim3(4, 4096), dim3(256), 0, stream>>>(b1, qbuf, 0);
    unfold_qk<<<dim3(4, 4096), dim3(256), 0, stream>>>(b3, kbuf, 1);
    unfold_v <<<dim3(16, NP),  dim3(256), 0, stream>>>(b2, vbuf);
    // score = 10 * q^T k   (hi/lo split, K=2432)
    gemm_nt<<<dim3(1024), dim3(256), 0, stream>>>(qbuf, KC, kbuf, KC,
                                                  score, LDC_S, 4096, KC, 10.0f);
    softmax_rows<<<dim3(4096), dim3(256), 0, stream>>>(score, att);
    // amv = att @ v^T   (M=4096, N=896, K=4096)
    gemm_nt<<<dim3(224), dim3(256), 0, stream>>>(att, 4096, vbuf, 4096,
                                                 amv, NP, NP, 4096, 1.0f);
    fold_norm<<<dim3(4096), dim3(256), 0, stream>>>(amv, zi);
    out_conv<<<dim3(256), dim3(256), 0, stream>>>(zi, bo, w_w, w_b, ob);
  }
}

// Round 2
// 2585.786 us; speedup vs baseline: 1.0479x; 1.0479x over previous
//
#include <hip/hip_runtime.h>
#include <cstdint>
#include <cstddef>

// ---------------- types ----------------
typedef __bf16 bf16_t;
typedef bf16_t bf16x8 __attribute__((ext_vector_type(8)));
typedef float  f32x4  __attribute__((ext_vector_type(4)));

#define GAS __attribute__((address_space(1)))
#define LAS __attribute__((address_space(3)))

__device__ __forceinline__ void g2l16(const void* g, void* l) {
  // async global->LDS, 16B per lane; LDS dest is wave-uniform base + lane*16
  __builtin_amdgcn_global_load_lds((const GAS unsigned int*)g,
                                   (LAS unsigned int*)l, 16, 0, 0);
}

// Problem constants
#define HW_  65536      // 256*256
#define NPIX 4096       // 64*64 patch grid
#define KC   2432       // 3*800 + 32 pad (hi/lo split concat K)
#define NPV  1024       // v rows padded to 1024 (784 real)

// ---------------- 1x1 convs: b1=gw*s+gb, b2=tw*g+tb, b3=pw*g+pb ----------------
__global__ __launch_bounds__(256) void conv1x1_3(
    const float* __restrict__ bo, const float* __restrict__ dg,
    const float* __restrict__ gw, const float* __restrict__ gb,
    const float* __restrict__ tw, const float* __restrict__ tb,
    const float* __restrict__ pw, const float* __restrict__ pb,
    float* __restrict__ b1, float* __restrict__ b2, float* __restrict__ b3)
{
  __shared__ float w1[1024], w2[1024], w3[1024], bia[48];
  int tid = threadIdx.x;
  for (int i = tid; i < 1024; i += 256) { w1[i] = gw[i]; w2[i] = tw[i]; w3[i] = pw[i]; }
  if (tid < 16) { bia[tid] = gb[tid]; bia[16 + tid] = tb[tid]; bia[32 + tid] = pb[tid]; }
  __syncthreads();
  int hw = blockIdx.x * 256 + tid;
  float a1[16], a2[16], a3[16];
#pragma unroll
  for (int o = 0; o < 16; ++o) { a1[o] = bia[o]; a2[o] = bia[16 + o]; a3[o] = bia[32 + o]; }
  for (int c = 0; c < 64; ++c) {
    float vs = bo[(size_t)c * HW_ + hw];
    float vg = dg[(size_t)c * HW_ + hw];
#pragma unroll
    for (int o = 0; o < 16; ++o) {
      a1[o] = fmaf(w1[o * 64 + c], vs, a1[o]);
      a2[o] = fmaf(w2[o * 64 + c], vg, a2[o]);
      a3[o] = fmaf(w3[o * 64 + c], vg, a3[o]);
    }
  }
#pragma unroll
  for (int o = 0; o < 16; ++o) {
    b1[(size_t)o * HW_ + hw] = a1[o];
    b2[(size_t)o * HW_ + hw] = a2[o];
    b3[(size_t)o * HW_ + hw] = a3[o];
  }
}

// ---------------- unfold (k=7,s=4,pad 1/2) into [4096][2432] bf16 hi/lo-split ----------------
// mode 0 (q): parts [hi | hi | lo] ; mode 1 (k): parts [hi | lo | hi]
// score = qhi*khi + qhi*klo + qlo*khi  (~fp32 accurate)
__global__ __launch_bounds__(256) void unfold_qk(const float* __restrict__ src,
                                                 bf16_t* __restrict__ dst, int mode)
{
  int kk = blockIdx.x * 256 + threadIdx.x;   // [0,1024) use [0,832)
  int i  = blockIdx.y;                        // patch index (oy*64+ox)
  if (kk >= 832) return;
  size_t rowoff = (size_t)i * KC;
  if (kk >= 800) { dst[rowoff + 1600 + kk] = (bf16_t)0.f; return; }  // [2400,2432) zeros
  float val = 0.f;
  if (kk < 784) {
    int c = kk / 49; int r = kk - c * 49; int ki = r / 7; int kj = r - ki * 7;
    int oy = i >> 6, ox = i & 63;
    int y = oy * 4 + ki - 1, x = ox * 4 + kj - 1;
    if ((unsigned)y < 256u && (unsigned)x < 256u) val = src[(size_t)c * HW_ + y * 256 + x];
  }
  bf16_t hi = (bf16_t)val;
  bf16_t lo = (bf16_t)(val - (float)hi);
  dst[rowoff + kk]        = hi;
  dst[rowoff + 800 + kk]  = mode ? lo : hi;
  dst[rowoff + 1600 + kk] = mode ? hi : lo;
}

// v unfold: vb[p][j], p in [0,1024), rows >=784 zero
__global__ __launch_bounds__(256) void unfold_v(const float* __restrict__ src,
                                                bf16_t* __restrict__ vb)
{
  int j = blockIdx.x * 256 + threadIdx.x;
  int p = blockIdx.y;
  float val = 0.f;
  if (p < 784) {
    int c = p / 49; int r = p - c * 49; int ki = r / 7; int kj = r - ki * 7;
    int oy = j >> 6, ox = j & 63;
    int y = oy * 4 + ki - 1, x = ox * 4 + kj - 1;
    if ((unsigned)y < 256u && (unsigned)x < 256u) val = src[(size_t)c * HW_ + y * 256 + x];
  }
  vb[(size_t)p * 4096 + j] = (bf16_t)val;
}

// ---------------- 256x256-tile GEMM: C = alpha * A(MxK) * B(NxK)^T, split-K capable ---------
// 8 waves (2M x 4N), BK=32, ring-4 LDS buffers (128 KiB), counted vmcnt, raw s_barrier.
// LDS layout per operand: kb-major cells [BK/8=4][256][8] -> linear gload_lds staging AND
// conflict-free ds_read_b128 fragment reads (contiguous 256B runs per 16-lane group).
__global__ __launch_bounds__(512, 2) void gemm256(
    const bf16_t* __restrict__ A, int lda,
    const bf16_t* __restrict__ B, int ldb,
    float* __restrict__ C, int ldc,
    int nbn, int bps, size_t csplit, int K, int kofs, float alpha)
{
  __shared__ __align__(16) bf16_t lds[4][2][1024][8];   // 128 KiB

  int nwg = gridDim.x, wg = blockIdx.x;
  int swz = ((nwg & 7) == 0) ? ((wg & 7) * (nwg >> 3) + (wg >> 3)) : wg;
  int s   = swz / bps;
  int rem = swz - s * bps;
  int bm  = rem / nbn, bn = rem - bm * nbn;
  A += (size_t)s * kofs;
  B += (size_t)s * kofs;
  C += (size_t)s * csplit;

  int tid  = threadIdx.x;
  int lane = tid & 63;
  int wid  = tid >> 6;
  int wr   = wid >> 2, wc = wid & 3;        // wave -> 128-row x 64-col output block
  int l16  = lane & 15, kb = lane >> 4;

  // staging: cell c (= issue*512 + tid) holds A[bm*256 + (c&255)][t*32 + (c>>8)*8 .. +7]
  const bf16_t* gA = A + (size_t)(bm * 256 + (tid & 255)) * lda + (tid >> 8) * 8;
  const bf16_t* gB = B + (size_t)(bn * 256 + (tid & 255)) * ldb + (tid >> 8) * 8;

  // LDS read base offsets (elements): cell = kb*256 + row
  int aoff = (kb * 256 + wr * 128 + l16) * 8;
  int boff = (kb * 256 + wc * 64  + l16) * 8;

  f32x4 acc[8][4];
#pragma unroll
  for (int f = 0; f < 8; ++f)
#pragma unroll
    for (int g2 = 0; g2 < 4; ++g2) acc[f][g2] = f32x4{0.f, 0.f, 0.f, 0.f};

  int T = K >> 5;
  int npro = T < 3 ? T : 3;
  for (int u = 0; u < npro; ++u) {          // prologue: stage tiles 0..2 (A then B)
    bf16_t* la = &lds[u][0][0][0];
    bf16_t* lb = &lds[u][1][0][0];
    const bf16_t* a0 = gA + (size_t)u * 32;
    const bf16_t* b0 = gB + (size_t)u * 32;
    g2l16(a0,      la + (size_t)tid * 8);
    g2l16(a0 + 16, la + (size_t)(512 + tid) * 8);
    g2l16(b0,      lb + (size_t)tid * 8);
    g2l16(b0 + 16, lb + (size_t)(512 + tid) * 8);
  }

  for (int t = 0; t < T; ++t) {
    // tile t's 4 issues are the oldest; outstanding newer = 4*min(T-1-t,2)
    int ahead = T - 1 - t;
    if (ahead >= 2)      asm volatile("s_waitcnt vmcnt(8)" ::: "memory");
    else if (ahead == 1) asm volatile("s_waitcnt vmcnt(4)" ::: "memory");
    else                 asm volatile("s_waitcnt vmcnt(0)" ::: "memory");
    __builtin_amdgcn_s_barrier();           // tile t visible to all; buf[(t+3)&3] free

    const bf16_t* ldsA = &lds[t & 3][0][0][0];
    const bf16_t* ldsB = &lds[t & 3][1][0][0];

    // ---- phase 0: stage A(t+3) | read B(all)+A(rh0) | MFMA rh0 quadrant ----
    if (t + 3 < T) {
      bf16_t* la = &lds[(t + 3) & 3][0][0][0];
      const bf16_t* a0 = gA + (size_t)(t + 3) * 32;
      g2l16(a0,      la + (size_t)tid * 8);
      g2l16(a0 + 16, la + (size_t)(512 + tid) * 8);
    }
    bf16x8 bg[4], af[4];
#pragma unroll
    for (int g2 = 0; g2 < 4; ++g2) bg[g2] = *(const bf16x8*)(ldsB + boff + g2 * 128);
#pragma unroll
    for (int f = 0; f < 4; ++f)    af[f]  = *(const bf16x8*)(ldsA + aoff + f * 128);
    __builtin_amdgcn_s_setprio(1);
#pragma unroll
    for (int f = 0; f < 4; ++f)
#pragma unroll
      for (int g2 = 0; g2 < 4; ++g2)
        acc[f][g2] = __builtin_amdgcn_mfma_f32_16x16x32_bf16(af[f], bg[g2], acc[f][g2], 0, 0, 0);
    __builtin_amdgcn_s_setprio(0);
    __builtin_amdgcn_s_barrier();

    // ---- phase 1: stage B(t+3) | read A(rh1) | MFMA rh1 quadrant ----
    if (t + 3 < T) {
      bf16_t* lb = &lds[(t + 3) & 3][1][0][0];
      const bf16_t* b0 = gB + (size_t)(t + 3) * 32;
      g2l16(b0,      lb + (size_t)tid * 8);
      g2l16(b0 + 16, lb + (size_t)(512 + tid) * 8);
    }
#pragma unroll
    for (int f = 0; f < 4; ++f) af[f] = *(const bf16x8*)(ldsA + aoff + 512 + f * 128);
    __builtin_amdgcn_s_setprio(1);
#pragma unroll
    for (int f = 0; f < 4; ++f)
#pragma unroll
      for (int g2 = 0; g2 < 4; ++g2)
        acc[4 + f][g2] = __builtin_amdgcn_mfma_f32_16x16x32_bf16(af[f], bg[g2], acc[4 + f][g2], 0, 0, 0);
    __builtin_amdgcn_s_setprio(0);
    // next iteration's vmcnt + barrier closes this phase
  }

  // C/D layout: col = lane&15, row = (lane>>4)*4 + reg ; frag rows = wr*128 + F*16
  int r0 = bm * 256 + wr * 128 + (lane >> 4) * 4;
  int c0 = bn * 256 + wc * 64 + l16;
#pragma unroll
  for (int f = 0; f < 8; ++f)
#pragma unroll
    for (int g2 = 0; g2 < 4; ++g2) {
      float* cp = C + (size_t)(r0 + f * 16) * ldc + c0 + g2 * 16;
#pragma unroll
      for (int r = 0; r < 4; ++r) cp[(size_t)r * ldc] = alpha * acc[f][g2][r];
    }
}

// ---------------- fused row softmax: att = softmax(score) as bf16 ----------------
__global__ __launch_bounds__(256) void softmax_rows(const float* __restrict__ S,
                                                    bf16_t* __restrict__ Att)
{
  int row = blockIdx.x;
  int tid = threadIdx.x;
  int lane = tid & 63, wid = tid >> 6;
  const float4* Sp = (const float4*)(S + (size_t)row * 4096);
  float4 vv[4];
  float m = -3.4e38f;
#pragma unroll
  for (int u = 0; u < 4; ++u) {
    vv[u] = Sp[u * 256 + tid];
    m = fmaxf(m, fmaxf(fmaxf(vv[u].x, vv[u].y), fmaxf(vv[u].z, vv[u].w)));
  }
#pragma unroll
  for (int off = 32; off; off >>= 1) m = fmaxf(m, __shfl_xor(m, off));
  __shared__ float redm[4], reds[4];
  if (lane == 0) redm[wid] = m;
  __syncthreads();
  m = fmaxf(fmaxf(redm[0], redm[1]), fmaxf(redm[2], redm[3]));
  float ssum = 0.f;
#pragma unroll
  for (int u = 0; u < 4; ++u) {
    vv[u].x = __expf(vv[u].x - m); vv[u].y = __expf(vv[u].y - m);
    vv[u].z = __expf(vv[u].z - m); vv[u].w = __expf(vv[u].w - m);
    ssum += vv[u].x + vv[u].y + vv[u].z + vv[u].w;
  }
#pragma unroll
  for (int off = 32; off; off >>= 1) ssum += __shfl_xor(ssum, off);
  if (lane == 0) reds[wid] = ssum;
  __syncthreads();
  float inv = 1.0f / (reds[0] + reds[1] + reds[2] + reds[3]);
  ushort4* Ap = (ushort4*)(Att + (size_t)row * 4096);
#pragma unroll
  for (int u = 0; u < 4; ++u) {
    union { bf16_t b[4]; ushort4 q; } pk;
    pk.b[0] = (bf16_t)(vv[u].x * inv);
    pk.b[1] = (bf16_t)(vv[u].y * inv);
    pk.b[2] = (bf16_t)(vv[u].z * inv);
    pk.b[3] = (bf16_t)(vv[u].w * inv);
    Ap[u * 256 + tid] = pk.q;
  }
}

// ---------------- split-K reduce: amv = sum_s part[s] ----------------
__global__ __launch_bounds__(256) void reduce4(const float4* __restrict__ part,
                                               float4* __restrict__ amv)
{
  size_t i = (size_t)blockIdx.x * 256 + threadIdx.x;   // over 1,048,576 float4
  const size_t S = (size_t)4096 * 1024 / 4;
  float4 a = part[i], b = part[i + S], c = part[i + 2 * S], d = part[i + 3 * S];
  float4 o;
  o.x = a.x + b.x + c.x + d.x;
  o.y = a.y + b.y + c.y + d.y;
  o.z = a.z + b.z + c.z + d.z;
  o.w = a.w + b.w + c.w + d.w;
  amv[i] = o;
}

// ---------------- fold (k=7,s=4,pad=3) + mask normalize -> zi[16][256][256] ----------------
__global__ __launch_bounds__(256) void fold_norm(const float* __restrict__ amv,
                                                 float* __restrict__ zi)
{
  int idx = blockIdx.x * 256 + threadIdx.x;   // c*65536 + h*256 + w
  int c = idx >> 16;
  int h = (idx >> 8) & 255;
  int w = idx & 255;
  int t = h + 3, u = w + 3;
  int oy0 = (t - 3) >> 2, oy1 = min(63, t >> 2);
  int ox0 = (u - 3) >> 2, ox1 = min(63, u >> 2);
  float sum = 0.f;
  for (int oy = oy0; oy <= oy1; ++oy) {
    int ki = t - oy * 4;
    for (int ox = ox0; ox <= ox1; ++ox) {
      int kj = u - ox * 4;
      sum += amv[(size_t)(oy * 64 + ox) * NPV + c * 49 + ki * 7 + kj];
    }
  }
  int cnt = (oy1 - oy0 + 1) * (ox1 - ox0 + 1);
  zi[idx] = sum / (float)cnt;
}

// ---------------- final: out = bo + w_w*zi + w_b ----------------
__global__ __launch_bounds__(256) void out_conv(const float* __restrict__ zi,
                                                const float* __restrict__ bo,
                                                const float* __restrict__ ww,
                                                const float* __restrict__ wb,
                                                float* __restrict__ outb)
{
  __shared__ float wws[1024], wbs[64];
  int tid = threadIdx.x;
  for (int i = tid; i < 1024; i += 256) wws[i] = ww[i];
  if (tid < 64) wbs[tid] = wb[tid];
  __syncthreads();
  int hw = blockIdx.x * 256 + tid;
  float z[16];
#pragma unroll
  for (int c = 0; c < 16; ++c) z[c] = zi[(size_t)c * HW_ + hw];
  for (int o = 0; o < 64; ++o) {
    float a = wbs[o];
#pragma unroll
    for (int c = 0; c < 16; ++c) a = fmaf(wws[o * 16 + c], z[c], a);
    outb[(size_t)o * HW_ + hw] = bo[(size_t)o * HW_ + hw] + a;
  }
}

// ---------------- host orchestration ----------------
static inline size_t alup(size_t x) { return (x + 255) & ~(size_t)255; }

extern "C" void kernel_launch(void* const* d_in, const int* in_sizes, int n_in,
                              void* d_out, int out_size, void* d_ws, size_t ws_size,
                              hipStream_t stream) {
  const float* s   = (const float*)d_in[0];
  const float* g   = (const float*)d_in[1];
  const float* g_w = (const float*)d_in[2];
  const float* g_b = (const float*)d_in[3];
  const float* t_w = (const float*)d_in[4];
  const float* t_b = (const float*)d_in[5];
  const float* p_w = (const float*)d_in[6];
  const float* p_b = (const float*)d_in[7];
  const float* w_w = (const float*)d_in[8];
  const float* w_b = (const float*)d_in[9];
  float* out = (float*)d_out;

  uint8_t* wp = (uint8_t*)d_ws;
  float*  b1    = (float*)wp;  wp += alup((size_t)16 * HW_ * 4);
  float*  b2    = (float*)wp;  wp += alup((size_t)16 * HW_ * 4);
  float*  b3    = (float*)wp;  wp += alup((size_t)16 * HW_ * 4);
  bf16_t* qbuf  = (bf16_t*)wp; wp += alup((size_t)NPIX * KC * 2);   // amv (16MB f32) aliases
  bf16_t* kbuf  = (bf16_t*)wp; wp += alup((size_t)NPIX * KC * 2);
  bf16_t* vbufp = (bf16_t*)wp; wp += alup((size_t)NPV * 4096 * 2);
  float*  score = (float*)wp;  wp += alup((size_t)NPIX * NPIX * 4); // part (64MB) aliases
  bf16_t* att   = (bf16_t*)wp; wp += alup((size_t)NPIX * NPIX * 2);
  float*  zi    = (float*)wp;  wp += alup((size_t)16 * HW_ * 4);
  float*  amv   = (float*)qbuf;    // qbuf dead after gemm1; amv consumed before next batch
  float*  part  = score;           // score dead after softmax; 4x4096x1024 f32 = 64MB exact

  for (int b = 0; b < 8; ++b) {
    const float* bo = s + (size_t)b * 64 * HW_;
    const float* dg = g + (size_t)b * 64 * HW_;
    float* ob = out + (size_t)b * 64 * HW_;

    conv1x1_3<<<dim3(256), dim3(256), 0, stream>>>(bo, dg, g_w, g_b, t_w, t_b, p_w, p_b,
                                                   b1, b2, b3);
    unfold_qk<<<dim3(4, 4096), dim3(256), 0, stream>>>(b1, qbuf, 0);
    unfold_qk<<<dim3(4, 4096), dim3(256), 0, stream>>>(b3, kbuf, 1);
    unfold_v <<<dim3(16, NPV), dim3(256), 0, stream>>>(b2, vbufp);
    // score = 10 * q k^T   (hi/lo split, K=2432), grid 256 = 1 wg/CU
    gemm256<<<dim3(256), dim3(512), 0, stream>>>(qbuf, KC, kbuf, KC, score, 4096,
                                                 16, 256, (size_t)0, KC, 0, 10.0f);
    softmax_rows<<<dim3(4096), dim3(256), 0, stream>>>(score, att);
    // amv_part[s] = att[:, s*1024:(s+1)*1024] @ v^T  (split-K=4, grid 4*64=256)
    gemm256<<<dim3(256), dim3(512), 0, stream>>>(att, 4096, vbufp, 4096, part, 1024,
                                                 4, 64, (size_t)4096 * 1024, 1024, 1024, 1.0f);
    reduce4<<<dim3(4096), dim3(256), 0, stream>>>((const float4*)part, (float4*)amv);
    fold_norm<<<dim3(4096), dim3(256), 0, stream>>>(amv, zi);
    out_conv<<<dim3(256), dim3(256), 0, stream>>>(zi, bo, w_w, w_b, ob);
  }
}

// Round 4
// 2575.560 us; speedup vs baseline: 1.0521x; 1.0040x over previous
//
#include <hip/hip_runtime.h>
#include <cstdint>
#include <cstddef>

// ---------------- types ----------------
typedef __bf16 bf16_t;
typedef bf16_t bf16x8 __attribute__((ext_vector_type(8)));
typedef float  f32x4  __attribute__((ext_vector_type(4)));

#define GAS __attribute__((address_space(1)))
#define LAS __attribute__((address_space(3)))

__device__ __forceinline__ void g2l16(const void* g, void* l) {
  // async global->LDS, 16B per lane; LDS dest is wave-uniform base + lane*16
  __builtin_amdgcn_global_load_lds((const GAS unsigned int*)g,
                                   (LAS unsigned int*)l, 16, 0, 0);
}

// Problem constants
#define HW_  65536      // 256*256
#define NPIX 4096       // 64*64 patch grid
#define KC   2432       // 3*800 + 32 pad (hi/lo split concat K)
#define NPV  1024       // v rows padded to 1024 (784 real)

// ---------------- 1x1 convs: b1=gw*s+gb, b2=tw*g+tb, b3=pw*g+pb ----------------
__global__ __launch_bounds__(256) void conv1x1_3(
    const float* __restrict__ bo, const float* __restrict__ dg,
    const float* __restrict__ gw, const float* __restrict__ gb,
    const float* __restrict__ tw, const float* __restrict__ tb,
    const float* __restrict__ pw, const float* __restrict__ pb,
    float* __restrict__ b1, float* __restrict__ b2, float* __restrict__ b3)
{
  __shared__ float w1[1024], w2[1024], w3[1024], bia[48];
  int tid = threadIdx.x;
  for (int i = tid; i < 1024; i += 256) { w1[i] = gw[i]; w2[i] = tw[i]; w3[i] = pw[i]; }
  if (tid < 16) { bia[tid] = gb[tid]; bia[16 + tid] = tb[tid]; bia[32 + tid] = pb[tid]; }
  __syncthreads();
  int hw = blockIdx.x * 256 + tid;
  float a1[16], a2[16], a3[16];
#pragma unroll
  for (int o = 0; o < 16; ++o) { a1[o] = bia[o]; a2[o] = bia[16 + o]; a3[o] = bia[32 + o]; }
  for (int c = 0; c < 64; ++c) {
    float vs = bo[(size_t)c * HW_ + hw];
    float vg = dg[(size_t)c * HW_ + hw];
#pragma unroll
    for (int o = 0; o < 16; ++o) {
      a1[o] = fmaf(w1[o * 64 + c], vs, a1[o]);
      a2[o] = fmaf(w2[o * 64 + c], vg, a2[o]);
      a3[o] = fmaf(w3[o * 64 + c], vg, a3[o]);
    }
  }
#pragma unroll
  for (int o = 0; o < 16; ++o) {
    b1[(size_t)o * HW_ + hw] = a1[o];
    b2[(size_t)o * HW_ + hw] = a2[o];
    b3[(size_t)o * HW_ + hw] = a3[o];
  }
}

// ---------------- unfold (k=7,s=4,pad 1/2) into [4096][2432] bf16 hi/lo-split ----------------
// mode 0 (q): parts [hi | hi | lo] ; mode 1 (k): parts [hi | lo | hi]
// score = qhi*khi + qhi*klo + qlo*khi  (~fp32 accurate)
__global__ __launch_bounds__(256) void unfold_qk(const float* __restrict__ src,
                                                 bf16_t* __restrict__ dst, int mode)
{
  int kk = blockIdx.x * 256 + threadIdx.x;   // [0,1024) use [0,832)
  int i  = blockIdx.y;                        // patch index (oy*64+ox)
  if (kk >= 832) return;
  size_t rowoff = (size_t)i * KC;
  if (kk >= 800) { dst[rowoff + 1600 + kk] = (bf16_t)0.f; return; }  // [2400,2432) zeros
  float val = 0.f;
  if (kk < 784) {
    int c = kk / 49; int r = kk - c * 49; int ki = r / 7; int kj = r - ki * 7;
    int oy = i >> 6, ox = i & 63;
    int y = oy * 4 + ki - 1, x = ox * 4 + kj - 1;
    if ((unsigned)y < 256u && (unsigned)x < 256u) val = src[(size_t)c * HW_ + y * 256 + x];
  }
  bf16_t hi = (bf16_t)val;
  bf16_t lo = (bf16_t)(val - (float)hi);
  dst[rowoff + kk]        = hi;
  dst[rowoff + 800 + kk]  = mode ? lo : hi;
  dst[rowoff + 1600 + kk] = mode ? hi : lo;
}

// v unfold: vb[p][j], p in [0,1024), rows >=784 zero
__global__ __launch_bounds__(256) void unfold_v(const float* __restrict__ src,
                                                bf16_t* __restrict__ vb)
{
  int j = blockIdx.x * 256 + threadIdx.x;
  int p = blockIdx.y;
  float val = 0.f;
  if (p < 784) {
    int c = p / 49; int r = p - c * 49; int ki = r / 7; int kj = r - ki * 7;
    int oy = j >> 6, ox = j & 63;
    int y = oy * 4 + ki - 1, x = ox * 4 + kj - 1;
    if ((unsigned)y < 256u && (unsigned)x < 256u) val = src[(size_t)c * HW_ + y * 256 + x];
  }
  vb[(size_t)p * 4096 + j] = (bf16_t)val;
}

// ---------------- 256x256-tile GEMM: C = alpha * A(MxK) * B(NxK)^T, split-K capable ---------
// 8 waves (2M x 4N), BK=32, ring-4 of STATICALLY-NAMED LDS buffers, K-loop unrolled x4 so
// every LDS access is object-static (lets waitcnt pass track LDS-DMA per object).
// Iteration order: {read tile-t high + tile-t+1 frags -> MFMA -> stage t+3 -> wait -> barrier}.
// Closing wait ledger: iter t's fragment reads need tiles t+1,t+2 resident at entry.
//   steady (t+3<T): outstanding = {t+2:4, t+3:4} -> vmcnt(4) leaves t+3 in flight. tail: vmcnt(0).
// REQUIRES: K % 128 == 0 (T=K/32 divisible by 4), T >= 4.
__global__ __launch_bounds__(512, 2) void gemm256(
    const bf16_t* __restrict__ A, int lda,
    const bf16_t* __restrict__ B, int ldb,
    float* __restrict__ C, int ldc,
    int nbn, int bps, size_t csplit, int K, int kofs, float alpha)
{
  // 8 x 16 KiB = 128 KiB. cell c in [0,1024): kb=c>>8 (K-group of 8), row=c&255.
  __shared__ __align__(16) bf16_t lA0[8192], lA1[8192], lA2[8192], lA3[8192];
  __shared__ __align__(16) bf16_t lB0[8192], lB1[8192], lB2[8192], lB3[8192];

  int nwg = gridDim.x, wg = blockIdx.x;
  int swz = ((nwg & 7) == 0) ? ((wg & 7) * (nwg >> 3) + (wg >> 3)) : wg;
  int s   = swz / bps;
  int rem = swz - s * bps;
  int bm  = rem / nbn, bn = rem - bm * nbn;
  A += (size_t)s * kofs;
  B += (size_t)s * kofs;
  C += (size_t)s * csplit;

  int tid  = threadIdx.x;
  int lane = tid & 63;
  int wid  = tid >> 6;
  int wr   = wid >> 2, wc = wid & 3;        // wave -> 128-row x 64-col output block
  int l16  = lane & 15, kb = lane >> 4;

  // staging: cell c (= issue*512 + tid) holds X[b*256 + (c&255)][t*32 + (c>>8)*8 .. +7]
  const bf16_t* gA = A + (size_t)(bm * 256 + (tid & 255)) * lda + (tid >> 8) * 8;
  const bf16_t* gB = B + (size_t)(bn * 256 + (tid & 255)) * ldb + (tid >> 8) * 8;

  // LDS read base offsets (elements): cell = kb*256 + row
  int aoff = (kb * 256 + wr * 128 + l16) * 8;
  int boff = (kb * 256 + wc * 64  + l16) * 8;

  f32x4 acc[8][4];
#pragma unroll
  for (int f = 0; f < 8; ++f)
#pragma unroll
    for (int q = 0; q < 4; ++q) acc[f][q] = f32x4{0.f, 0.f, 0.f, 0.f};

  int T = K >> 5;

  // prologue: stage tiles 0,1,2 into buffers 0,1,2 (A then B per tile)
  g2l16(gA,      lA0 + (size_t)tid * 8);  g2l16(gA + 16, lA0 + (size_t)(512 + tid) * 8);
  g2l16(gB,      lB0 + (size_t)tid * 8);  g2l16(gB + 16, lB0 + (size_t)(512 + tid) * 8);
  if (T > 1) {
    g2l16(gA + 32, lA1 + (size_t)tid * 8); g2l16(gA + 48, lA1 + (size_t)(512 + tid) * 8);
    g2l16(gB + 32, lB1 + (size_t)tid * 8); g2l16(gB + 48, lB1 + (size_t)(512 + tid) * 8);
  }
  if (T > 2) {
    g2l16(gA + 64, lA2 + (size_t)tid * 8); g2l16(gA + 80, lA2 + (size_t)(512 + tid) * 8);
    g2l16(gB + 64, lB2 + (size_t)tid * 8); g2l16(gB + 80, lB2 + (size_t)(512 + tid) * 8);
  }
  if (T > 2) { asm volatile("s_waitcnt vmcnt(4)" ::: "memory"); }  // tiles 0,1 resident
  else       { asm volatile("s_waitcnt vmcnt(0)" ::: "memory"); }
  __builtin_amdgcn_s_barrier();

  // preload tile 0 fragments (B all 4 col-groups of wave's 64, A rows 0..63 of wave's 128)
  bf16x8 bgc[4], afl[4], bgn[4], afn[4];
#pragma unroll
  for (int q = 0; q < 4; ++q) bgc[q] = *(const bf16x8*)(lB0 + boff + q * 128);
#pragma unroll
  for (int f = 0; f < 4; ++f) afl[f] = *(const bf16x8*)(lA0 + aoff + f * 128);
#pragma unroll
  for (int q = 0; q < 4; ++q) bgn[q] = bgc[q];
#pragma unroll
  for (int f = 0; f < 4; ++f) afn[f] = afl[f];

  // One iteration: tile t resident in (LCA,LCB); t+1 in (LNA,LNB); stage t+3 into (LSA,LSB).
#define GITER(t, LCA, LCB, LNA, LNB, LSA, LSB)                                          \
  {                                                                                      \
    bf16x8 afh[4];                                                                       \
    _Pragma("unroll") for (int f = 0; f < 4; ++f)                                        \
      afh[f] = *(const bf16x8*)(LCA + aoff + 512 + f * 128);                             \
    __builtin_amdgcn_s_setprio(1);                                                       \
    _Pragma("unroll") for (int f = 0; f < 4; ++f)                                        \
      _Pragma("unroll") for (int q = 0; q < 4; ++q)                                      \
        acc[f][q] = __builtin_amdgcn_mfma_f32_16x16x32_bf16(afl[f], bgc[q], acc[f][q], 0, 0, 0); \
    __builtin_amdgcn_s_setprio(0);                                                       \
    if ((t) + 1 < T) {                                                                   \
      _Pragma("unroll") for (int q = 0; q < 4; ++q)                                      \
        bgn[q] = *(const bf16x8*)(LNB + boff + q * 128);                                 \
      _Pragma("unroll") for (int f = 0; f < 4; ++f)                                      \
        afn[f] = *(const bf16x8*)(LNA + aoff + f * 128);                                 \
    }                                                                                    \
    __builtin_amdgcn_s_setprio(1);                                                       \
    _Pragma("unroll") for (int f = 0; f < 4; ++f)                                        \
      _Pragma("unroll") for (int q = 0; q < 4; ++q)                                      \
        acc[4 + f][q] = __builtin_amdgcn_mfma_f32_16x16x32_bf16(afh[f], bgc[q], acc[4 + f][q], 0, 0, 0); \
    __builtin_amdgcn_s_setprio(0);                                                       \
    if ((t) + 3 < T) {                                                                   \
      const bf16_t* sa = gA + (size_t)((t) + 3) * 32;                                    \
      const bf16_t* sb = gB + (size_t)((t) + 3) * 32;                                    \
      g2l16(sa,      LSA + (size_t)tid * 8);  g2l16(sa + 16, LSA + (size_t)(512 + tid) * 8); \
      g2l16(sb,      LSB + (size_t)tid * 8);  g2l16(sb + 16, LSB + (size_t)(512 + tid) * 8); \
      asm volatile("s_waitcnt vmcnt(4)" ::: "memory");  /* t+2 resident, t+3 in flight */ \
    } else {                                                                             \
      asm volatile("s_waitcnt vmcnt(0)" ::: "memory");  /* tail: drain everything */     \
    }                                                                                    \
    __builtin_amdgcn_s_barrier();                                                        \
    _Pragma("unroll") for (int q = 0; q < 4; ++q) bgc[q] = bgn[q];                       \
    _Pragma("unroll") for (int f = 0; f < 4; ++f) afl[f] = afn[f];                       \
  }

  for (int t0 = 0; t0 < T; t0 += 4) {
    GITER(t0 + 0, lA0, lB0, lA1, lB1, lA3, lB3)
    GITER(t0 + 1, lA1, lB1, lA2, lB2, lA0, lB0)
    GITER(t0 + 2, lA2, lB2, lA3, lB3, lA1, lB1)
    GITER(t0 + 3, lA3, lB3, lA0, lB0, lA2, lB2)
  }
#undef GITER

  // C/D layout: col = lane&15, row = (lane>>4)*4 + reg ; frag rows = wr*128 + F*16
  int r0 = bm * 256 + wr * 128 + (lane >> 4) * 4;
  int c0 = bn * 256 + wc * 64 + l16;
#pragma unroll
  for (int f = 0; f < 8; ++f)
#pragma unroll
    for (int q = 0; q < 4; ++q) {
      float* cp = C + (size_t)(r0 + f * 16) * ldc + c0 + q * 16;
#pragma unroll
      for (int r = 0; r < 4; ++r) cp[(size_t)r * ldc] = alpha * acc[f][q][r];
    }
}

// ---------------- fused row softmax: att = softmax(score) as bf16 ----------------
__global__ __launch_bounds__(256) void softmax_rows(const float* __restrict__ S,
                                                    bf16_t* __restrict__ Att)
{
  int row = blockIdx.x;
  int tid = threadIdx.x;
  int lane = tid & 63, wid = tid >> 6;
  const float4* Sp = (const float4*)(S + (size_t)row * 4096);
  float4 vv[4];
  float m = -3.4e38f;
#pragma unroll
  for (int u = 0; u < 4; ++u) {
    vv[u] = Sp[u * 256 + tid];
    m = fmaxf(m, fmaxf(fmaxf(vv[u].x, vv[u].y), fmaxf(vv[u].z, vv[u].w)));
  }
#pragma unroll
  for (int off = 32; off; off >>= 1) m = fmaxf(m, __shfl_xor(m, off));
  __shared__ float redm[4], reds[4];
  if (lane == 0) redm[wid] = m;
  __syncthreads();
  m = fmaxf(fmaxf(redm[0], redm[1]), fmaxf(redm[2], redm[3]));
  float ssum = 0.f;
#pragma unroll
  for (int u = 0; u < 4; ++u) {
    vv[u].x = __expf(vv[u].x - m); vv[u].y = __expf(vv[u].y - m);
    vv[u].z = __expf(vv[u].z - m); vv[u].w = __expf(vv[u].w - m);
    ssum += vv[u].x + vv[u].y + vv[u].z + vv[u].w;
  }
#pragma unroll
  for (int off = 32; off; off >>= 1) ssum += __shfl_xor(ssum, off);
  if (lane == 0) reds[wid] = ssum;
  __syncthreads();
  float inv = 1.0f / (reds[0] + reds[1] + reds[2] + reds[3]);
  ushort4* Ap = (ushort4*)(Att + (size_t)row * 4096);
#pragma unroll
  for (int u = 0; u < 4; ++u) {
    union { bf16_t b[4]; ushort4 q; } pk;
    pk.b[0] = (bf16_t)(vv[u].x * inv);
    pk.b[1] = (bf16_t)(vv[u].y * inv);
    pk.b[2] = (bf16_t)(vv[u].z * inv);
    pk.b[3] = (bf16_t)(vv[u].w * inv);
    Ap[u * 256 + tid] = pk.q;
  }
}

// ---------------- split-K reduce: amv = sum_s part[s] ----------------
__global__ __launch_bounds__(256) void reduce4(const float4* __restrict__ part,
                                               float4* __restrict__ amv)
{
  size_t i = (size_t)blockIdx.x * 256 + threadIdx.x;   // over 1,048,576 float4
  const size_t S = (size_t)4096 * 1024 / 4;
  float4 a = part[i], b = part[i + S], c = part[i + 2 * S], d = part[i + 3 * S];
  float4 o;
  o.x = a.x + b.x + c.x + d.x;
  o.y = a.y + b.y + c.y + d.y;
  o.z = a.z + b.z + c.z + d.z;
  o.w = a.w + b.w + c.w + d.w;
  amv[i] = o;
}

// ---------------- fold (k=7,s=4,pad=3) + mask normalize -> zi[16][256][256] ----------------
__global__ __launch_bounds__(256) void fold_norm(const float* __restrict__ amv,
                                                 float* __restrict__ zi)
{
  int idx = blockIdx.x * 256 + threadIdx.x;   // c*65536 + h*256 + w
  int c = idx >> 16;
  int h = (idx >> 8) & 255;
  int w = idx & 255;
  int t = h + 3, u = w + 3;
  int oy0 = (t - 3) >> 2, oy1 = min(63, t >> 2);
  int ox0 = (u - 3) >> 2, ox1 = min(63, u >> 2);
  float sum = 0.f;
  for (int oy = oy0; oy <= oy1; ++oy) {
    int ki = t - oy * 4;
    for (int ox = ox0; ox <= ox1; ++ox) {
      int kj = u - ox * 4;
      sum += amv[(size_t)(oy * 64 + ox) * NPV + c * 49 + ki * 7 + kj];
    }
  }
  int cnt = (oy1 - oy0 + 1) * (ox1 - ox0 + 1);
  zi[idx] = sum / (float)cnt;
}

// ---------------- final: out = bo + w_w*zi + w_b ----------------
__global__ __launch_bounds__(256) void out_conv(const float* __restrict__ zi,
                                                const float* __restrict__ bo,
                                                const float* __restrict__ ww,
                                                const float* __restrict__ wb,
                                                float* __restrict__ outb)
{
  __shared__ float wws[1024], wbs[64];
  int tid = threadIdx.x;
  for (int i = tid; i < 1024; i += 256) wws[i] = ww[i];
  if (tid < 64) wbs[tid] = wb[tid];
  __syncthreads();
  int hw = blockIdx.x * 256 + tid;
  float z[16];
#pragma unroll
  for (int c = 0; c < 16; ++c) z[c] = zi[(size_t)c * HW_ + hw];
  for (int o = 0; o < 64; ++o) {
    float a = wbs[o];
#pragma unroll
    for (int c = 0; c < 16; ++c) a = fmaf(wws[o * 16 + c], z[c], a);
    outb[(size_t)o * HW_ + hw] = bo[(size_t)o * HW_ + hw] + a;
  }
}

// ---------------- host orchestration ----------------
static inline size_t alup(size_t x) { return (x + 255) & ~(size_t)255; }

extern "C" void kernel_launch(void* const* d_in, const int* in_sizes, int n_in,
                              void* d_out, int out_size, void* d_ws, size_t ws_size,
                              hipStream_t stream) {
  const float* s   = (const float*)d_in[0];
  const float* g   = (const float*)d_in[1];
  const float* g_w = (const float*)d_in[2];
  const float* g_b = (const float*)d_in[3];
  const float* t_w = (const float*)d_in[4];
  const float* t_b = (const float*)d_in[5];
  const float* p_w = (const float*)d_in[6];
  const float* p_b = (const float*)d_in[7];
  const float* w_w = (const float*)d_in[8];
  const float* w_b = (const float*)d_in[9];
  float* out = (float*)d_out;

  uint8_t* wp = (uint8_t*)d_ws;
  float*  b1    = (float*)wp;  wp += alup((size_t)16 * HW_ * 4);
  float*  b2    = (float*)wp;  wp += alup((size_t)16 * HW_ * 4);
  float*  b3    = (float*)wp;  wp += alup((size_t)16 * HW_ * 4);
  bf16_t* qbuf  = (bf16_t*)wp; wp += alup((size_t)NPIX * KC * 2);   // amv (16MB f32) aliases
  bf16_t* kbuf  = (bf16_t*)wp; wp += alup((size_t)NPIX * KC * 2);
  bf16_t* vbufp = (bf16_t*)wp; wp += alup((size_t)NPV * 4096 * 2);
  float*  score = (float*)wp;  wp += alup((size_t)NPIX * NPIX * 4); // part (64MB) aliases
  bf16_t* att   = (bf16_t*)wp; wp += alup((size_t)NPIX * NPIX * 2);
  float*  zi    = (float*)wp;  wp += alup((size_t)16 * HW_ * 4);
  float*  amv   = (float*)qbuf;    // qbuf dead after gemm1; amv consumed before next batch
  float*  part  = score;           // score dead after softmax; 4x4096x1024 f32 = 64MB exact

  for (int b = 0; b < 8; ++b) {
    const float* bo = s + (size_t)b * 64 * HW_;
    const float* dg = g + (size_t)b * 64 * HW_;
    float* ob = out + (size_t)b * 64 * HW_;

    conv1x1_3<<<dim3(256), dim3(256), 0, stream>>>(bo, dg, g_w, g_b, t_w, t_b, p_w, p_b,
                                                   b1, b2, b3);
    unfold_qk<<<dim3(4, 4096), dim3(256), 0, stream>>>(b1, qbuf, 0);
    unfold_qk<<<dim3(4, 4096), dim3(256), 0, stream>>>(b3, kbuf, 1);
    unfold_v <<<dim3(16, NPV), dim3(256), 0, stream>>>(b2, vbufp);
    // score = 10 * q k^T   (hi/lo split, K=2432 -> T=76), grid 256 = 1 wg/CU
    gemm256<<<dim3(256), dim3(512), 0, stream>>>(qbuf, KC, kbuf, KC, score, 4096,
                                                 16, 256, (size_t)0, KC, 0, 10.0f);
    softmax_rows<<<dim3(4096), dim3(256), 0, stream>>>(score, att);
    // amv_part[s] = att[:, s*1024:(s+1)*1024] @ v^T  (split-K=4, T=32, grid 4*64=256)
    gemm256<<<dim3(256), dim3(512), 0, stream>>>(att, 4096, vbufp, 4096, part, 1024,
                                                 4, 64, (size_t)4096 * 1024, 1024, 1024, 1.0f);
    reduce4<<<dim3(4096), dim3(256), 0, stream>>>((const float4*)part, (float4*)amv);
    fold_norm<<<dim3(4096), dim3(256), 0, stream>>>(amv, zi);
    out_conv<<<dim3(256), dim3(256), 0, stream>>>(zi, bo, w_w, w_b, ob);
  }
}

// Round 5
// 2422.070 us; speedup vs baseline: 1.1187x; 1.0634x over previous
//
#include <hip/hip_runtime.h>
#include <cstdint>
#include <cstddef>

// ---------------- types ----------------
typedef __bf16 bf16_t;
typedef bf16_t bf16x8 __attribute__((ext_vector_type(8)));
typedef float  f32x4  __attribute__((ext_vector_type(4)));

#define GAS __attribute__((address_space(1)))
#define LAS __attribute__((address_space(3)))

__device__ __forceinline__ void g2l16(const void* g, void* l) {
  // async global->LDS, 16B per lane; LDS dest is wave-uniform base + lane*16
  __builtin_amdgcn_global_load_lds((const GAS unsigned int*)g,
                                   (LAS unsigned int*)l, 16, 0, 0);
}

// Problem constants
#define HW_  65536      // 256*256
#define NPIX 4096       // 64*64 patch grid
#define KC   2432       // 3*800 + 32 pad (hi/lo split concat K)
#define NPV  1024       // v rows padded to 1024 (784 real)

// ---------------- 1x1 convs: b1=gw*s+gb, b2=tw*g+tb, b3=pw*g+pb ----------------
__global__ __launch_bounds__(256) void conv1x1_3(
    const float* __restrict__ bo, const float* __restrict__ dg,
    const float* __restrict__ gw, const float* __restrict__ gb,
    const float* __restrict__ tw, const float* __restrict__ tb,
    const float* __restrict__ pw, const float* __restrict__ pb,
    float* __restrict__ b1, float* __restrict__ b2, float* __restrict__ b3)
{
  __shared__ float w1[1024], w2[1024], w3[1024], bia[48];
  int tid = threadIdx.x;
  for (int i = tid; i < 1024; i += 256) { w1[i] = gw[i]; w2[i] = tw[i]; w3[i] = pw[i]; }
  if (tid < 16) { bia[tid] = gb[tid]; bia[16 + tid] = tb[tid]; bia[32 + tid] = pb[tid]; }
  __syncthreads();
  int hw = blockIdx.x * 256 + tid;
  float a1[16], a2[16], a3[16];
#pragma unroll
  for (int o = 0; o < 16; ++o) { a1[o] = bia[o]; a2[o] = bia[16 + o]; a3[o] = bia[32 + o]; }
  for (int c = 0; c < 64; ++c) {
    float vs = bo[(size_t)c * HW_ + hw];
    float vg = dg[(size_t)c * HW_ + hw];
#pragma unroll
    for (int o = 0; o < 16; ++o) {
      a1[o] = fmaf(w1[o * 64 + c], vs, a1[o]);
      a2[o] = fmaf(w2[o * 64 + c], vg, a2[o]);
      a3[o] = fmaf(w3[o * 64 + c], vg, a3[o]);
    }
  }
#pragma unroll
  for (int o = 0; o < 16; ++o) {
    b1[(size_t)o * HW_ + hw] = a1[o];
    b2[(size_t)o * HW_ + hw] = a2[o];
    b3[(size_t)o * HW_ + hw] = a3[o];
  }
}

// ---------------- unfold (k=7,s=4,pad 1/2) into [4096][2432] bf16 hi/lo-split ----------------
// mode 0 (q): parts [hi | hi | lo] ; mode 1 (k): parts [hi | lo | hi]
// score = qhi*khi + qhi*klo + qlo*khi  (~fp32 accurate)
__global__ __launch_bounds__(256) void unfold_qk(const float* __restrict__ src,
                                                 bf16_t* __restrict__ dst, int mode)
{
  int kk = blockIdx.x * 256 + threadIdx.x;   // [0,1024) use [0,832)
  int i  = blockIdx.y;                        // patch index (oy*64+ox)
  if (kk >= 832) return;
  size_t rowoff = (size_t)i * KC;
  if (kk >= 800) { dst[rowoff + 1600 + kk] = (bf16_t)0.f; return; }  // [2400,2432) zeros
  float val = 0.f;
  if (kk < 784) {
    int c = kk / 49; int r = kk - c * 49; int ki = r / 7; int kj = r - ki * 7;
    int oy = i >> 6, ox = i & 63;
    int y = oy * 4 + ki - 1, x = ox * 4 + kj - 1;
    if ((unsigned)y < 256u && (unsigned)x < 256u) val = src[(size_t)c * HW_ + y * 256 + x];
  }
  bf16_t hi = (bf16_t)val;
  bf16_t lo = (bf16_t)(val - (float)hi);
  dst[rowoff + kk]        = hi;
  dst[rowoff + 800 + kk]  = mode ? lo : hi;
  dst[rowoff + 1600 + kk] = mode ? hi : lo;
}

// v unfold: vb[p][j], p in [0,1024), rows >=784 zero
__global__ __launch_bounds__(256) void unfold_v(const float* __restrict__ src,
                                                bf16_t* __restrict__ vb)
{
  int j = blockIdx.x * 256 + threadIdx.x;
  int p = blockIdx.y;
  float val = 0.f;
  if (p < 784) {
    int c = p / 49; int r = p - c * 49; int ki = r / 7; int kj = r - ki * 7;
    int oy = j >> 6, ox = j & 63;
    int y = oy * 4 + ki - 1, x = ox * 4 + kj - 1;
    if ((unsigned)y < 256u && (unsigned)x < 256u) val = src[(size_t)c * HW_ + y * 256 + x];
  }
  vb[(size_t)p * 4096 + j] = (bf16_t)val;
}

// ---------------- 256x256-tile GEMM, 8-phase schedule: C = alpha*A(MxK)*B(NxK)^T -----------
// 8 waves (2M x 4N), BK=64 split in two K-halves of 32. LDS = ring of 8 x 16KiB half-slots.
// Tile t occupies slots (t&1)*4 + {0:Ak0, 1:Bk0, 2:Ak1, 3:Bk1}.
// Phase schedule per tile t (4 phases, each: reads -> stage 1 half -> barrier -> lgkmcnt(0)
// -> 16 MFMA -> barrier). Stage map: ph0: Ak1(t+1); ph1: Bk0(t+2); ph2: Ak0(t+2); ph3:
// Bk1(t+2) then vmcnt(6) [vmcnt(0) at t==T-2] before the tile-boundary barrier.
// Ledger: entry vmcnt(6) retires {Bk0,Ak0,Bk1}(t) staged 3 phases back + Ak1(t) staged 4 back;
// every slot overwrite happens exactly >=1 barrier-separated phase after that slot's last read.
// REQUIRES: K % 64 == 0, T = K/64 >= 3.
__global__ __launch_bounds__(512, 2) void gemm256(
    const bf16_t* __restrict__ A, int lda,
    const bf16_t* __restrict__ B, int ldb,
    float* __restrict__ C, int ldc,
    int nbn, int bps, size_t csplit, int K, int kofs, float alpha)
{
  __shared__ __align__(16) bf16_t lds[8][8192];   // 8 half-slots x 16 KiB = 128 KiB

  int nwg = gridDim.x, wg = blockIdx.x;
  int swz = ((nwg & 7) == 0) ? ((wg & 7) * (nwg >> 3) + (wg >> 3)) : wg;
  int s   = swz / bps;
  int rem = swz - s * bps;
  int bm  = rem / nbn, bn = rem - bm * nbn;
  A += (size_t)s * kofs;
  B += (size_t)s * kofs;
  C += (size_t)s * csplit;

  int tid  = threadIdx.x;
  int lane = tid & 63;
  int wid  = tid >> 6;
  int wr   = wid >> 2, wc = wid & 3;        // wave -> 128-row x 64-col output block
  int l16  = lane & 15;

  // staging: instr u stages cell u*512+tid of a half-slot; cell = kb*256+row,
  // kb = u*2 + (tid>>8), row = tid&255; global k-elem offset = half_kofs + kb*8.
  const bf16_t* gA = A + (size_t)(bm * 256 + (tid & 255)) * lda + (tid >> 8) * 8;
  const bf16_t* gB = B + (size_t)(bn * 256 + (tid & 255)) * ldb + (tid >> 8) * 8;

#define STAGE(gsrc, koffe, slot) {                                   \
    const bf16_t* _s = (gsrc) + (koffe);                             \
    g2l16(_s,      &lds[slot][(size_t)tid * 8]);                     \
    g2l16(_s + 16, &lds[slot][(size_t)(512 + tid) * 8]); }

  // fragment read offsets (elements) within a half-slot: cell = (lane>>4)*256 + row
  int aoff = ((lane >> 4) * 256 + wr * 128 + l16) * 8;
  int boff = ((lane >> 4) * 256 + wc * 64 + l16) * 8;

  f32x4 acc[8][4];
#pragma unroll
  for (int f = 0; f < 8; ++f)
#pragma unroll
    for (int q = 0; q < 4; ++q) acc[f][q] = f32x4{0.f, 0.f, 0.f, 0.f};

  int T = K >> 6;   // BK = 64

  // prologue: 7 halves in steady-state order (phases -7..-1)
  STAGE(gB, 0, 1)        // Bk0(0)
  STAGE(gA, 0, 0)        // Ak0(0)
  STAGE(gB, 32, 3)       // Bk1(0)
  STAGE(gA, 32, 2)       // Ak1(0)
  STAGE(gB, 64, 5)       // Bk0(1)
  STAGE(gA, 64, 4)       // Ak0(1)
  STAGE(gB, 96, 7)       // Bk1(1)
  asm volatile("s_waitcnt vmcnt(6)" ::: "memory");   // tile 0 fully resident
  __builtin_amdgcn_s_barrier();

  for (int t = 0; t < T; ++t) {
    int pi = (t & 1) * 4;          // current tile's slot base
    int po = ((t + 1) & 1) * 4;    // other parity
    const bf16_t* sAk0 = &lds[pi + 0][0];
    const bf16_t* sBk0 = &lds[pi + 1][0];
    const bf16_t* sAk1 = &lds[pi + 2][0];
    const bf16_t* sBk1 = &lds[pi + 3][0];
    bf16x8 bg[4], af[4];

    // ---- phase 0: read B(ks0) + A(ks0, rf0-3) | stage Ak1(t+1) | MFMA q0 ----
#pragma unroll
    for (int q = 0; q < 4; ++q) bg[q] = *(const bf16x8*)(sBk0 + boff + q * 128);
#pragma unroll
    for (int f = 0; f < 4; ++f) af[f] = *(const bf16x8*)(sAk0 + aoff + f * 128);
    if (t + 1 < T) STAGE(gA, (t + 1) * 64 + 32, po + 2)
    __builtin_amdgcn_s_barrier();
    asm volatile("s_waitcnt lgkmcnt(0)" ::: "memory");
    __builtin_amdgcn_sched_barrier(0);
    __builtin_amdgcn_s_setprio(1);
#pragma unroll
    for (int f = 0; f < 4; ++f)
#pragma unroll
      for (int q = 0; q < 4; ++q)
        acc[f][q] = __builtin_amdgcn_mfma_f32_16x16x32_bf16(af[f], bg[q], acc[f][q], 0, 0, 0);
    __builtin_amdgcn_s_setprio(0);
    __builtin_amdgcn_s_barrier();

    // ---- phase 1: read A(ks0, rf4-7) | stage Bk0(t+2) | MFMA q1 ----
#pragma unroll
    for (int f = 0; f < 4; ++f) af[f] = *(const bf16x8*)(sAk0 + aoff + 512 + f * 128);
    if (t + 2 < T) STAGE(gB, (t + 2) * 64, pi + 1)
    __builtin_amdgcn_s_barrier();
    asm volatile("s_waitcnt lgkmcnt(0)" ::: "memory");
    __builtin_amdgcn_sched_barrier(0);
    __builtin_amdgcn_s_setprio(1);
#pragma unroll
    for (int f = 0; f < 4; ++f)
#pragma unroll
      for (int q = 0; q < 4; ++q)
        acc[4 + f][q] = __builtin_amdgcn_mfma_f32_16x16x32_bf16(af[f], bg[q], acc[4 + f][q], 0, 0, 0);
    __builtin_amdgcn_s_setprio(0);
    __builtin_amdgcn_s_barrier();

    // ---- phase 2: read B(ks1) + A(ks1, rf0-3) | stage Ak0(t+2) | MFMA q2 ----
#pragma unroll
    for (int q = 0; q < 4; ++q) bg[q] = *(const bf16x8*)(sBk1 + boff + q * 128);
#pragma unroll
    for (int f = 0; f < 4; ++f) af[f] = *(const bf16x8*)(sAk1 + aoff + f * 128);
    if (t + 2 < T) STAGE(gA, (t + 2) * 64, pi + 0)
    __builtin_amdgcn_s_barrier();
    asm volatile("s_waitcnt lgkmcnt(0)" ::: "memory");
    __builtin_amdgcn_sched_barrier(0);
    __builtin_amdgcn_s_setprio(1);
#pragma unroll
    for (int f = 0; f < 4; ++f)
#pragma unroll
      for (int q = 0; q < 4; ++q)
        acc[f][q] = __builtin_amdgcn_mfma_f32_16x16x32_bf16(af[f], bg[q], acc[f][q], 0, 0, 0);
    __builtin_amdgcn_s_setprio(0);
    __builtin_amdgcn_s_barrier();

    // ---- phase 3: read A(ks1, rf4-7) | stage Bk1(t+2) | MFMA q3 | boundary vmcnt ----
#pragma unroll
    for (int f = 0; f < 4; ++f) af[f] = *(const bf16x8*)(sAk1 + aoff + 512 + f * 128);
    if (t + 2 < T) STAGE(gB, (t + 2) * 64 + 32, pi + 3)
    __builtin_amdgcn_s_barrier();
    asm volatile("s_waitcnt lgkmcnt(0)" ::: "memory");
    __builtin_amdgcn_sched_barrier(0);
    __builtin_amdgcn_s_setprio(1);
#pragma unroll
    for (int f = 0; f < 4; ++f)
#pragma unroll
      for (int q = 0; q < 4; ++q)
        acc[4 + f][q] = __builtin_amdgcn_mfma_f32_16x16x32_bf16(af[f], bg[q], acc[4 + f][q], 0, 0, 0);
    __builtin_amdgcn_s_setprio(0);
    if (t < T - 2)       { asm volatile("s_waitcnt vmcnt(6)" ::: "memory"); }
    else if (t == T - 2) { asm volatile("s_waitcnt vmcnt(0)" ::: "memory"); }
    __builtin_amdgcn_s_barrier();
  }
#undef STAGE

  // C/D layout: col = lane&15, row = (lane>>4)*4 + reg ; frag rows = wr*128 + F*16
  int r0 = bm * 256 + wr * 128 + (lane >> 4) * 4;
  int c0 = bn * 256 + wc * 64 + l16;
#pragma unroll
  for (int f = 0; f < 8; ++f)
#pragma unroll
    for (int q = 0; q < 4; ++q) {
      float* cp = C + (size_t)(r0 + f * 16) * ldc + c0 + q * 16;
#pragma unroll
      for (int r = 0; r < 4; ++r) cp[(size_t)r * ldc] = alpha * acc[f][q][r];
    }
}

// ---------------- fused row softmax: att = softmax(score) as bf16 ----------------
__global__ __launch_bounds__(256) void softmax_rows(const float* __restrict__ S,
                                                    bf16_t* __restrict__ Att)
{
  int row = blockIdx.x;
  int tid = threadIdx.x;
  int lane = tid & 63, wid = tid >> 6;
  const float4* Sp = (const float4*)(S + (size_t)row * 4096);
  float4 vv[4];
  float m = -3.4e38f;
#pragma unroll
  for (int u = 0; u < 4; ++u) {
    vv[u] = Sp[u * 256 + tid];
    m = fmaxf(m, fmaxf(fmaxf(vv[u].x, vv[u].y), fmaxf(vv[u].z, vv[u].w)));
  }
#pragma unroll
  for (int off = 32; off; off >>= 1) m = fmaxf(m, __shfl_xor(m, off));
  __shared__ float redm[4], reds[4];
  if (lane == 0) redm[wid] = m;
  __syncthreads();
  m = fmaxf(fmaxf(redm[0], redm[1]), fmaxf(redm[2], redm[3]));
  float ssum = 0.f;
#pragma unroll
  for (int u = 0; u < 4; ++u) {
    vv[u].x = __expf(vv[u].x - m); vv[u].y = __expf(vv[u].y - m);
    vv[u].z = __expf(vv[u].z - m); vv[u].w = __expf(vv[u].w - m);
    ssum += vv[u].x + vv[u].y + vv[u].z + vv[u].w;
  }
#pragma unroll
  for (int off = 32; off; off >>= 1) ssum += __shfl_xor(ssum, off);
  if (lane == 0) reds[wid] = ssum;
  __syncthreads();
  float inv = 1.0f / (reds[0] + reds[1] + reds[2] + reds[3]);
  ushort4* Ap = (ushort4*)(Att + (size_t)row * 4096);
#pragma unroll
  for (int u = 0; u < 4; ++u) {
    union { bf16_t b[4]; ushort4 q; } pk;
    pk.b[0] = (bf16_t)(vv[u].x * inv);
    pk.b[1] = (bf16_t)(vv[u].y * inv);
    pk.b[2] = (bf16_t)(vv[u].z * inv);
    pk.b[3] = (bf16_t)(vv[u].w * inv);
    Ap[u * 256 + tid] = pk.q;
  }
}

// ---------------- split-K reduce: amv = sum_s part[s] ----------------
__global__ __launch_bounds__(256) void reduce4(const float4* __restrict__ part,
                                               float4* __restrict__ amv)
{
  size_t i = (size_t)blockIdx.x * 256 + threadIdx.x;   // over 1,048,576 float4
  const size_t S = (size_t)4096 * 1024 / 4;
  float4 a = part[i], b = part[i + S], c = part[i + 2 * S], d = part[i + 3 * S];
  float4 o;
  o.x = a.x + b.x + c.x + d.x;
  o.y = a.y + b.y + c.y + d.y;
  o.z = a.z + b.z + c.z + d.z;
  o.w = a.w + b.w + c.w + d.w;
  amv[i] = o;
}

// ---------------- fold (k=7,s=4,pad=3) + mask normalize -> zi[16][256][256] ----------------
__global__ __launch_bounds__(256) void fold_norm(const float* __restrict__ amv,
                                                 float* __restrict__ zi)
{
  int idx = blockIdx.x * 256 + threadIdx.x;   // c*65536 + h*256 + w
  int c = idx >> 16;
  int h = (idx >> 8) & 255;
  int w = idx & 255;
  int t = h + 3, u = w + 3;
  int oy0 = (t - 3) >> 2, oy1 = min(63, t >> 2);
  int ox0 = (u - 3) >> 2, ox1 = min(63, u >> 2);
  float sum = 0.f;
  for (int oy = oy0; oy <= oy1; ++oy) {
    int ki = t - oy * 4;
    for (int ox = ox0; ox <= ox1; ++ox) {
      int kj = u - ox * 4;
      sum += amv[(size_t)(oy * 64 + ox) * NPV + c * 49 + ki * 7 + kj];
    }
  }
  int cnt = (oy1 - oy0 + 1) * (ox1 - ox0 + 1);
  zi[idx] = sum / (float)cnt;
}

// ---------------- final: out = bo + w_w*zi + w_b ----------------
__global__ __launch_bounds__(256) void out_conv(const float* __restrict__ zi,
                                                const float* __restrict__ bo,
                                                const float* __restrict__ ww,
                                                const float* __restrict__ wb,
                                                float* __restrict__ outb)
{
  __shared__ float wws[1024], wbs[64];
  int tid = threadIdx.x;
  for (int i = tid; i < 1024; i += 256) wws[i] = ww[i];
  if (tid < 64) wbs[tid] = wb[tid];
  __syncthreads();
  int hw = blockIdx.x * 256 + tid;
  float z[16];
#pragma unroll
  for (int c = 0; c < 16; ++c) z[c] = zi[(size_t)c * HW_ + hw];
  for (int o = 0; o < 64; ++o) {
    float a = wbs[o];
#pragma unroll
    for (int c = 0; c < 16; ++c) a = fmaf(wws[o * 16 + c], z[c], a);
    outb[(size_t)o * HW_ + hw] = bo[(size_t)o * HW_ + hw] + a;
  }
}

// ---------------- host orchestration ----------------
static inline size_t alup(size_t x) { return (x + 255) & ~(size_t)255; }

extern "C" void kernel_launch(void* const* d_in, const int* in_sizes, int n_in,
                              void* d_out, int out_size, void* d_ws, size_t ws_size,
                              hipStream_t stream) {
  const float* s   = (const float*)d_in[0];
  const float* g   = (const float*)d_in[1];
  const float* g_w = (const float*)d_in[2];
  const float* g_b = (const float*)d_in[3];
  const float* t_w = (const float*)d_in[4];
  const float* t_b = (const float*)d_in[5];
  const float* p_w = (const float*)d_in[6];
  const float* p_b = (const float*)d_in[7];
  const float* w_w = (const float*)d_in[8];
  const float* w_b = (const float*)d_in[9];
  float* out = (float*)d_out;

  uint8_t* wp = (uint8_t*)d_ws;
  float*  b1    = (float*)wp;  wp += alup((size_t)16 * HW_ * 4);
  float*  b2    = (float*)wp;  wp += alup((size_t)16 * HW_ * 4);
  float*  b3    = (float*)wp;  wp += alup((size_t)16 * HW_ * 4);
  bf16_t* qbuf  = (bf16_t*)wp; wp += alup((size_t)NPIX * KC * 2);   // amv (16MB f32) aliases
  bf16_t* kbuf  = (bf16_t*)wp; wp += alup((size_t)NPIX * KC * 2);
  bf16_t* vbufp = (bf16_t*)wp; wp += alup((size_t)NPV * 4096 * 2);
  float*  score = (float*)wp;  wp += alup((size_t)NPIX * NPIX * 4); // part (64MB) aliases
  bf16_t* att   = (bf16_t*)wp; wp += alup((size_t)NPIX * NPIX * 2);
  float*  zi    = (float*)wp;  wp += alup((size_t)16 * HW_ * 4);
  float*  amv   = (float*)qbuf;    // qbuf dead after gemm1; amv consumed before next batch
  float*  part  = score;           // score dead after softmax; 4x4096x1024 f32 = 64MB exact

  for (int b = 0; b < 8; ++b) {
    const float* bo = s + (size_t)b * 64 * HW_;
    const float* dg = g + (size_t)b * 64 * HW_;
    float* ob = out + (size_t)b * 64 * HW_;

    conv1x1_3<<<dim3(256), dim3(256), 0, stream>>>(bo, dg, g_w, g_b, t_w, t_b, p_w, p_b,
                                                   b1, b2, b3);
    unfold_qk<<<dim3(4, 4096), dim3(256), 0, stream>>>(b1, qbuf, 0);
    unfold_qk<<<dim3(4, 4096), dim3(256), 0, stream>>>(b3, kbuf, 1);
    unfold_v <<<dim3(16, NPV), dim3(256), 0, stream>>>(b2, vbufp);
    // score = 10 * q k^T   (hi/lo split, K=2432 -> T=38), grid 256 = 1 wg/CU
    gemm256<<<dim3(256), dim3(512), 0, stream>>>(qbuf, KC, kbuf, KC, score, 4096,
                                                 16, 256, (size_t)0, KC, 0, 10.0f);
    softmax_rows<<<dim3(4096), dim3(256), 0, stream>>>(score, att);
    // amv_part[s] = att[:, s*1024:(s+1)*1024] @ v^T  (split-K=4, T=16, grid 4*64=256)
    gemm256<<<dim3(256), dim3(512), 0, stream>>>(att, 4096, vbufp, 4096, part, 1024,
                                                 4, 64, (size_t)4096 * 1024, 1024, 1024, 1.0f);
    reduce4<<<dim3(4096), dim3(256), 0, stream>>>((const float4*)part, (float4*)amv);
    fold_norm<<<dim3(4096), dim3(256), 0, stream>>>(amv, zi);
    out_conv<<<dim3(256), dim3(256), 0, stream>>>(zi, bo, w_w, w_b, ob);
  }
}

// Round 6
// 1875.826 us; speedup vs baseline: 1.4445x; 1.2912x over previous
//
#include <hip/hip_runtime.h>
#include <cstdint>
#include <cstddef>

// ---------------- types ----------------
typedef __bf16 bf16_t;
typedef _Float16 fp16_t;
typedef bf16_t bf16x8 __attribute__((ext_vector_type(8)));
typedef fp16_t fp16x8 __attribute__((ext_vector_type(8)));
typedef float  f32x4  __attribute__((ext_vector_type(4)));

#define GAS __attribute__((address_space(1)))
#define LAS __attribute__((address_space(3)))

__device__ __forceinline__ void g2l16(const void* g, void* l) {
  // async global->LDS, 16B per lane; LDS dest is wave-uniform base + lane*16
  __builtin_amdgcn_global_load_lds((const GAS unsigned int*)g,
                                   (LAS unsigned int*)l, 16, 0, 0);
}

__device__ __forceinline__ f32x4 mfma16(bf16x8 a, bf16x8 b, f32x4 c) {
  return __builtin_amdgcn_mfma_f32_16x16x32_bf16(a, b, c, 0, 0, 0);
}
__device__ __forceinline__ f32x4 mfma16(fp16x8 a, fp16x8 b, f32x4 c) {
  return __builtin_amdgcn_mfma_f32_16x16x32_f16(a, b, c, 0, 0, 0);
}
template <typename T> struct vec8;
template <> struct vec8<bf16_t> { using t = bf16x8; };
template <> struct vec8<fp16_t> { using t = fp16x8; };

// Problem constants
#define HW_  65536      // 256*256
#define NPIX 4096       // 64*64 patch grid
#define KQ   832        // 784 real + pad to 832 (fp16 single-pass)
#define NPV  1024       // v rows padded to 1024 (784 real)

// ---------------- 1x1 convs: b1=gw*s+gb, b2=tw*g+tb, b3=pw*g+pb ----------------
__global__ __launch_bounds__(256) void conv1x1_3(
    const float* __restrict__ bo, const float* __restrict__ dg,
    const float* __restrict__ gw, const float* __restrict__ gb,
    const float* __restrict__ tw, const float* __restrict__ tb,
    const float* __restrict__ pw, const float* __restrict__ pb,
    float* __restrict__ b1, float* __restrict__ b2, float* __restrict__ b3)
{
  __shared__ float w1[1024], w2[1024], w3[1024], bia[48];
  int tid = threadIdx.x;
  for (int i = tid; i < 1024; i += 256) { w1[i] = gw[i]; w2[i] = tw[i]; w3[i] = pw[i]; }
  if (tid < 16) { bia[tid] = gb[tid]; bia[16 + tid] = tb[tid]; bia[32 + tid] = pb[tid]; }
  __syncthreads();
  int hw = blockIdx.x * 256 + tid;
  float a1[16], a2[16], a3[16];
#pragma unroll
  for (int o = 0; o < 16; ++o) { a1[o] = bia[o]; a2[o] = bia[16 + o]; a3[o] = bia[32 + o]; }
  for (int c = 0; c < 64; ++c) {
    float vs = bo[(size_t)c * HW_ + hw];
    float vg = dg[(size_t)c * HW_ + hw];
#pragma unroll
    for (int o = 0; o < 16; ++o) {
      a1[o] = fmaf(w1[o * 64 + c], vs, a1[o]);
      a2[o] = fmaf(w2[o * 64 + c], vg, a2[o]);
      a3[o] = fmaf(w3[o * 64 + c], vg, a3[o]);
    }
  }
#pragma unroll
  for (int o = 0; o < 16; ++o) {
    b1[(size_t)o * HW_ + hw] = a1[o];
    b2[(size_t)o * HW_ + hw] = a2[o];
    b3[(size_t)o * HW_ + hw] = a3[o];
  }
}

// ---------------- unfold (k=7,s=4,pad 1/2) into [4096][832] fp16 ----------------
__global__ __launch_bounds__(256) void unfold_qk(const float* __restrict__ src,
                                                 fp16_t* __restrict__ dst)
{
  int kk = blockIdx.x * 256 + threadIdx.x;   // [0,1024) use [0,832)
  int i  = blockIdx.y;                        // patch index (oy*64+ox)
  if (kk >= KQ) return;
  float val = 0.f;
  if (kk < 784) {
    int c = kk / 49; int r = kk - c * 49; int ki = r / 7; int kj = r - ki * 7;
    int oy = i >> 6, ox = i & 63;
    int y = oy * 4 + ki - 1, x = ox * 4 + kj - 1;
    if ((unsigned)y < 256u && (unsigned)x < 256u) val = src[(size_t)c * HW_ + y * 256 + x];
  }
  dst[(size_t)i * KQ + kk] = (fp16_t)val;
}

// v unfold: vb[p][j], p in [0,1024), rows >=784 zero
__global__ __launch_bounds__(256) void unfold_v(const float* __restrict__ src,
                                                bf16_t* __restrict__ vb)
{
  int j = blockIdx.x * 256 + threadIdx.x;
  int p = blockIdx.y;
  float val = 0.f;
  if (p < 784) {
    int c = p / 49; int r = p - c * 49; int ki = r / 7; int kj = r - ki * 7;
    int oy = j >> 6, ox = j & 63;
    int y = oy * 4 + ki - 1, x = ox * 4 + kj - 1;
    if ((unsigned)y < 256u && (unsigned)x < 256u) val = src[(size_t)c * HW_ + y * 256 + x];
  }
  vb[(size_t)p * 4096 + j] = (bf16_t)val;
}

// ---------------- 256x256-tile GEMM, 8-phase schedule: C = alpha*A(MxK)*B(NxK)^T -----------
// 8 waves (2M x 4N), BK=64 in two K-halves of 32. LDS = ring of 8 x 16KiB half-slots.
// Tile t occupies slots (t&1)*4 + {0:Ak0, 1:Bk0, 2:Ak1, 3:Bk1}.
// Per phase: {ds_read frags -> stage 1 half -> barrier -> lgkmcnt(0) -> 16 MFMA -> barrier};
// boundary vmcnt(6) per tile (vmcnt(0) at t==T-2). REQUIRES: K % 64 == 0, T = K/64 >= 3.
template <typename T>
__global__ __launch_bounds__(512, 2) void gemm256(
    const T* __restrict__ A, int lda,
    const T* __restrict__ B, int ldb,
    float* __restrict__ C, int ldc,
    int nbn, int bps, size_t csplit, int K, int kofs, float alpha)
{
  using v8t = typename vec8<T>::t;
  __shared__ __align__(16) T lds[8][8192];   // 8 half-slots x 16 KiB = 128 KiB

  int nwg = gridDim.x, wg = blockIdx.x;
  int swz = ((nwg & 7) == 0) ? ((wg & 7) * (nwg >> 3) + (wg >> 3)) : wg;
  int s   = swz / bps;
  int rem = swz - s * bps;
  int bm  = rem / nbn, bn = rem - bm * nbn;
  A += (size_t)s * kofs;
  B += (size_t)s * kofs;
  C += (size_t)s * csplit;

  int tid  = threadIdx.x;
  int lane = tid & 63;
  int wid  = tid >> 6;
  int wr   = wid >> 2, wc = wid & 3;        // wave -> 128-row x 64-col output block
  int l16  = lane & 15;

  // staging: instr u stages cell u*512+tid; cell = kb*256+row, kb = u*2+(tid>>8),
  // row = tid&255; global k-elem offset = half_kofs + kb*8.
  const T* gA = A + (size_t)(bm * 256 + (tid & 255)) * lda + (tid >> 8) * 8;
  const T* gB = B + (size_t)(bn * 256 + (tid & 255)) * ldb + (tid >> 8) * 8;

#define STAGE(gsrc, koffe, slot) {                                   \
    const T* _s = (gsrc) + (koffe);                                  \
    g2l16(_s,      &lds[slot][(size_t)tid * 8]);                     \
    g2l16(_s + 16, &lds[slot][(size_t)(512 + tid) * 8]); }

  // fragment read offsets (elements) within a half-slot: cell = (lane>>4)*256 + row
  int aoff = ((lane >> 4) * 256 + wr * 128 + l16) * 8;
  int boff = ((lane >> 4) * 256 + wc * 64 + l16) * 8;

  f32x4 acc[8][4];
#pragma unroll
  for (int f = 0; f < 8; ++f)
#pragma unroll
    for (int q = 0; q < 4; ++q) acc[f][q] = f32x4{0.f, 0.f, 0.f, 0.f};

  int T_ = K >> 6;   // BK = 64

  // prologue: 7 halves in steady-state order
  STAGE(gB, 0, 1)        // Bk0(0)
  STAGE(gA, 0, 0)        // Ak0(0)
  STAGE(gB, 32, 3)       // Bk1(0)
  STAGE(gA, 32, 2)       // Ak1(0)
  STAGE(gB, 64, 5)       // Bk0(1)
  STAGE(gA, 64, 4)       // Ak0(1)
  STAGE(gB, 96, 7)       // Bk1(1)
  asm volatile("s_waitcnt vmcnt(6)" ::: "memory");   // tile 0 fully resident
  __builtin_amdgcn_s_barrier();

  for (int t = 0; t < T_; ++t) {
    int pi = (t & 1) * 4;          // current tile's slot base
    int po = ((t + 1) & 1) * 4;    // other parity
    const T* sAk0 = &lds[pi + 0][0];
    const T* sBk0 = &lds[pi + 1][0];
    const T* sAk1 = &lds[pi + 2][0];
    const T* sBk1 = &lds[pi + 3][0];
    v8t bg[4], af[4];

    // ---- phase 0: read B(ks0) + A(ks0, rf0-3) | stage Ak1(t+1) | MFMA q0 ----
#pragma unroll
    for (int q = 0; q < 4; ++q) bg[q] = *(const v8t*)(sBk0 + boff + q * 128);
#pragma unroll
    for (int f = 0; f < 4; ++f) af[f] = *(const v8t*)(sAk0 + aoff + f * 128);
    if (t + 1 < T_) STAGE(gA, (t + 1) * 64 + 32, po + 2)
    __builtin_amdgcn_s_barrier();
    asm volatile("s_waitcnt lgkmcnt(0)" ::: "memory");
    __builtin_amdgcn_sched_barrier(0);
    __builtin_amdgcn_s_setprio(1);
#pragma unroll
    for (int f = 0; f < 4; ++f)
#pragma unroll
      for (int q = 0; q < 4; ++q)
        acc[f][q] = mfma16(af[f], bg[q], acc[f][q]);
    __builtin_amdgcn_s_setprio(0);
    __builtin_amdgcn_s_barrier();

    // ---- phase 1: read A(ks0, rf4-7) | stage Bk0(t+2) | MFMA q1 ----
#pragma unroll
    for (int f = 0; f < 4; ++f) af[f] = *(const v8t*)(sAk0 + aoff + 512 + f * 128);
    if (t + 2 < T_) STAGE(gB, (t + 2) * 64, pi + 1)
    __builtin_amdgcn_s_barrier();
    asm volatile("s_waitcnt lgkmcnt(0)" ::: "memory");
    __builtin_amdgcn_sched_barrier(0);
    __builtin_amdgcn_s_setprio(1);
#pragma unroll
    for (int f = 0; f < 4; ++f)
#pragma unroll
      for (int q = 0; q < 4; ++q)
        acc[4 + f][q] = mfma16(af[f], bg[q], acc[4 + f][q]);
    __builtin_amdgcn_s_setprio(0);
    __builtin_amdgcn_s_barrier();

    // ---- phase 2: read B(ks1) + A(ks1, rf0-3) | stage Ak0(t+2) | MFMA q2 ----
#pragma unroll
    for (int q = 0; q < 4; ++q) bg[q] = *(const v8t*)(sBk1 + boff + q * 128);
#pragma unroll
    for (int f = 0; f < 4; ++f) af[f] = *(const v8t*)(sAk1 + aoff + f * 128);
    if (t + 2 < T_) STAGE(gA, (t + 2) * 64, pi + 0)
    __builtin_amdgcn_s_barrier();
    asm volatile("s_waitcnt lgkmcnt(0)" ::: "memory");
    __builtin_amdgcn_sched_barrier(0);
    __builtin_amdgcn_s_setprio(1);
#pragma unroll
    for (int f = 0; f < 4; ++f)
#pragma unroll
      for (int q = 0; q < 4; ++q)
        acc[f][q] = mfma16(af[f], bg[q], acc[f][q]);
    __builtin_amdgcn_s_setprio(0);
    __builtin_amdgcn_s_barrier();

    // ---- phase 3: read A(ks1, rf4-7) | stage Bk1(t+2) | MFMA q3 | boundary vmcnt ----
#pragma unroll
    for (int f = 0; f < 4; ++f) af[f] = *(const v8t*)(sAk1 + aoff + 512 + f * 128);
    if (t + 2 < T_) STAGE(gB, (t + 2) * 64 + 32, pi + 3)
    __builtin_amdgcn_s_barrier();
    asm volatile("s_waitcnt lgkmcnt(0)" ::: "memory");
    __builtin_amdgcn_sched_barrier(0);
    __builtin_amdgcn_s_setprio(1);
#pragma unroll
    for (int f = 0; f < 4; ++f)
#pragma unroll
      for (int q = 0; q < 4; ++q)
        acc[4 + f][q] = mfma16(af[f], bg[q], acc[4 + f][q]);
    __builtin_amdgcn_s_setprio(0);
    if (t < T_ - 2)       { asm volatile("s_waitcnt vmcnt(6)" ::: "memory"); }
    else if (t == T_ - 2) { asm volatile("s_waitcnt vmcnt(0)" ::: "memory"); }
    __builtin_amdgcn_s_barrier();
  }
#undef STAGE

  // C/D layout: col = lane&15, row = (lane>>4)*4 + reg ; frag rows = wr*128 + F*16
  int r0 = bm * 256 + wr * 128 + (lane >> 4) * 4;
  int c0 = bn * 256 + wc * 64 + l16;
#pragma unroll
  for (int f = 0; f < 8; ++f)
#pragma unroll
    for (int q = 0; q < 4; ++q) {
      float* cp = C + (size_t)(r0 + f * 16) * ldc + c0 + q * 16;
#pragma unroll
      for (int r = 0; r < 4; ++r) cp[(size_t)r * ldc] = alpha * acc[f][q][r];
    }
}

// ---------------- fused row softmax: att = softmax(score) as bf16 ----------------
__global__ __launch_bounds__(256) void softmax_rows(const float* __restrict__ S,
                                                    bf16_t* __restrict__ Att)
{
  int row = blockIdx.x;
  int tid = threadIdx.x;
  int lane = tid & 63, wid = tid >> 6;
  const float4* Sp = (const float4*)(S + (size_t)row * 4096);
  float4 vv[4];
  float m = -3.4e38f;
#pragma unroll
  for (int u = 0; u < 4; ++u) {
    vv[u] = Sp[u * 256 + tid];
    m = fmaxf(m, fmaxf(fmaxf(vv[u].x, vv[u].y), fmaxf(vv[u].z, vv[u].w)));
  }
#pragma unroll
  for (int off = 32; off; off >>= 1) m = fmaxf(m, __shfl_xor(m, off));
  __shared__ float redm[4], reds[4];
  if (lane == 0) redm[wid] = m;
  __syncthreads();
  m = fmaxf(fmaxf(redm[0], redm[1]), fmaxf(redm[2], redm[3]));
  float ssum = 0.f;
#pragma unroll
  for (int u = 0; u < 4; ++u) {
    vv[u].x = __expf(vv[u].x - m); vv[u].y = __expf(vv[u].y - m);
    vv[u].z = __expf(vv[u].z - m); vv[u].w = __expf(vv[u].w - m);
    ssum += vv[u].x + vv[u].y + vv[u].z + vv[u].w;
  }
#pragma unroll
  for (int off = 32; off; off >>= 1) ssum += __shfl_xor(ssum, off);
  if (lane == 0) reds[wid] = ssum;
  __syncthreads();
  float inv = 1.0f / (reds[0] + reds[1] + reds[2] + reds[3]);
  ushort4* Ap = (ushort4*)(Att + (size_t)row * 4096);
#pragma unroll
  for (int u = 0; u < 4; ++u) {
    union { bf16_t b[4]; ushort4 q; } pk;
    pk.b[0] = (bf16_t)(vv[u].x * inv);
    pk.b[1] = (bf16_t)(vv[u].y * inv);
    pk.b[2] = (bf16_t)(vv[u].z * inv);
    pk.b[3] = (bf16_t)(vv[u].w * inv);
    Ap[u * 256 + tid] = pk.q;
  }
}

// ---------------- split-K reduce: amv = sum_s part[s] ----------------
__global__ __launch_bounds__(256) void reduce4(const float4* __restrict__ part,
                                               float4* __restrict__ amv)
{
  size_t i = (size_t)blockIdx.x * 256 + threadIdx.x;   // over 1,048,576 float4
  const size_t S = (size_t)4096 * 1024 / 4;
  float4 a = part[i], b = part[i + S], c = part[i + 2 * S], d = part[i + 3 * S];
  float4 o;
  o.x = a.x + b.x + c.x + d.x;
  o.y = a.y + b.y + c.y + d.y;
  o.z = a.z + b.z + c.z + d.z;
  o.w = a.w + b.w + c.w + d.w;
  amv[i] = o;
}

// ---------------- fold (k=7,s=4,pad=3) + mask normalize -> zi[16][256][256] ----------------
__global__ __launch_bounds__(256) void fold_norm(const float* __restrict__ amv,
                                                 float* __restrict__ zi)
{
  int idx = blockIdx.x * 256 + threadIdx.x;   // c*65536 + h*256 + w
  int c = idx >> 16;
  int h = (idx >> 8) & 255;
  int w = idx & 255;
  int t = h + 3, u = w + 3;
  int oy0 = (t - 3) >> 2, oy1 = min(63, t >> 2);
  int ox0 = (u - 3) >> 2, ox1 = min(63, u >> 2);
  float sum = 0.f;
  for (int oy = oy0; oy <= oy1; ++oy) {
    int ki = t - oy * 4;
    for (int ox = ox0; ox <= ox1; ++ox) {
      int kj = u - ox * 4;
      sum += amv[(size_t)(oy * 64 + ox) * NPV + c * 49 + ki * 7 + kj];
    }
  }
  int cnt = (oy1 - oy0 + 1) * (ox1 - ox0 + 1);
  zi[idx] = sum / (float)cnt;
}

// ---------------- final: out = bo + w_w*zi + w_b ----------------
__global__ __launch_bounds__(256) void out_conv(const float* __restrict__ zi,
                                                const float* __restrict__ bo,
                                                const float* __restrict__ ww,
                                                const float* __restrict__ wb,
                                                float* __restrict__ outb)
{
  __shared__ float wws[1024], wbs[64];
  int tid = threadIdx.x;
  for (int i = tid; i < 1024; i += 256) wws[i] = ww[i];
  if (tid < 64) wbs[tid] = wb[tid];
  __syncthreads();
  int hw = blockIdx.x * 256 + tid;
  float z[16];
#pragma unroll
  for (int c = 0; c < 16; ++c) z[c] = zi[(size_t)c * HW_ + hw];
  for (int o = 0; o < 64; ++o) {
    float a = wbs[o];
#pragma unroll
    for (int c = 0; c < 16; ++c) a = fmaf(wws[o * 16 + c], z[c], a);
    outb[(size_t)o * HW_ + hw] = bo[(size_t)o * HW_ + hw] + a;
  }
}

// ---------------- host orchestration ----------------
static inline size_t alup(size_t x) { return (x + 255) & ~(size_t)255; }

extern "C" void kernel_launch(void* const* d_in, const int* in_sizes, int n_in,
                              void* d_out, int out_size, void* d_ws, size_t ws_size,
                              hipStream_t stream) {
  const float* s   = (const float*)d_in[0];
  const float* g   = (const float*)d_in[1];
  const float* g_w = (const float*)d_in[2];
  const float* g_b = (const float*)d_in[3];
  const float* t_w = (const float*)d_in[4];
  const float* t_b = (const float*)d_in[5];
  const float* p_w = (const float*)d_in[6];
  const float* p_b = (const float*)d_in[7];
  const float* w_w = (const float*)d_in[8];
  const float* w_b = (const float*)d_in[9];
  float* out = (float*)d_out;

  uint8_t* wp = (uint8_t*)d_ws;
  float*  b1    = (float*)wp;  wp += alup((size_t)16 * HW_ * 4);
  float*  b2    = (float*)wp;  wp += alup((size_t)16 * HW_ * 4);
  float*  b3    = (float*)wp;  wp += alup((size_t)16 * HW_ * 4);
  fp16_t* qbuf  = (fp16_t*)wp; wp += alup((size_t)NPIX * KQ * 2);
  fp16_t* kbuf  = (fp16_t*)wp; wp += alup((size_t)NPIX * KQ * 2);
  bf16_t* vbufp = (bf16_t*)wp; wp += alup((size_t)NPV * 4096 * 2);
  float*  score = (float*)wp;  wp += alup((size_t)NPIX * NPIX * 4); // part (64MB) aliases
  bf16_t* att   = (bf16_t*)wp; wp += alup((size_t)NPIX * NPIX * 2);
  float*  zi    = (float*)wp;  wp += alup((size_t)16 * HW_ * 4);
  float*  amv   = (float*)wp;  wp += alup((size_t)NPIX * NPV * 4);
  float*  part  = score;           // score dead after softmax; 4x4096x1024 f32 = 64MB exact
  // total ~151 MB (was ~161 MB in the round-5 layout)

  for (int b = 0; b < 8; ++b) {
    const float* bo = s + (size_t)b * 64 * HW_;
    const float* dg = g + (size_t)b * 64 * HW_;
    float* ob = out + (size_t)b * 64 * HW_;

    conv1x1_3<<<dim3(256), dim3(256), 0, stream>>>(bo, dg, g_w, g_b, t_w, t_b, p_w, p_b,
                                                   b1, b2, b3);
    unfold_qk<<<dim3(4, 4096), dim3(256), 0, stream>>>(b1, qbuf);
    unfold_qk<<<dim3(4, 4096), dim3(256), 0, stream>>>(b3, kbuf);
    unfold_v <<<dim3(16, NPV), dim3(256), 0, stream>>>(b2, vbufp);
    // score = 10 * q k^T   (fp16 single-pass, K=832 -> T=13), grid 256 = 1 wg/CU
    gemm256<fp16_t><<<dim3(256), dim3(512), 0, stream>>>(qbuf, KQ, kbuf, KQ, score, 4096,
                                                         16, 256, (size_t)0, KQ, 0, 10.0f);
    softmax_rows<<<dim3(4096), dim3(256), 0, stream>>>(score, att);
    // amv_part[s] = att[:, s*1024:(s+1)*1024] @ v^T  (split-K=4, T=16, grid 4*64=256)
    gemm256<bf16_t><<<dim3(256), dim3(512), 0, stream>>>(att, 4096, vbufp, 4096, part, 1024,
                                                         4, 64, (size_t)4096 * 1024, 1024, 1024, 1.0f);
    reduce4<<<dim3(4096), dim3(256), 0, stream>>>((const float4*)part, (float4*)amv);
    fold_norm<<<dim3(4096), dim3(256), 0, stream>>>(amv, zi);
    out_conv<<<dim3(256), dim3(256), 0, stream>>>(zi, bo, w_w, w_b, ob);
  }
}